// Round 13
// baseline (282.721 us; speedup 1.0000x reference)
//
#include <hip/hip_runtime.h>
#include <hip/hip_bf16.h>
#include <hip/hip_fp8.h>

#define NN 100000
#define NE 1600000
#define FF 128
#define HH 128
#define CC 10
#define GG 64

#define NCHUNK 2048
#define CE 782            // ceil(NE/NCHUNK)
#define NBUCKET 128
#define BSPAN 782         // ceil(NN/NBUCKET)
#define CAP 16384         // per-bucket capacity (mean 12500, sigma ~111)
#define XCONV_BLOCKS 6250 // NN*HH/8/256
#define PSEG 16

typedef __attribute__((ext_vector_type(8))) short short8;
typedef __attribute__((ext_vector_type(4))) float f32x4;
typedef __attribute__((ext_vector_type(2))) float f32x2;

__device__ inline unsigned short f2bf(float f) {
    union { float f; unsigned int i; } x;
    x.f = f;
    unsigned int r = x.i + 0x7FFF + ((x.i >> 16) & 1);  // RNE
    return (unsigned short)(r >> 16);
}
__device__ inline unsigned char f8enc(float v) {
    __hip_fp8_e4m3 q(v);
    return (unsigned char)q.__x;
}
__device__ inline float f8dec(unsigned char b) {
    __hip_fp8_e4m3 q;
    q.__x = (__hip_fp8_storage_t)b;
    return (float)q;
}

#if defined(__has_builtin)
#if __has_builtin(__builtin_amdgcn_cvt_pk_f32_fp8)
#define HAVE_CVT_PK_F32_FP8 1
#endif
#endif

// decode 8 fp8 (uint2) -> 8 f32 (scalar out)
__device__ inline void dec8(uint2 v, float* o) {
#ifdef HAVE_CVT_PK_F32_FP8
    f32x2 p;
    p = __builtin_amdgcn_cvt_pk_f32_fp8(v.x, false); o[0] = p[0]; o[1] = p[1];
    p = __builtin_amdgcn_cvt_pk_f32_fp8(v.x, true);  o[2] = p[0]; o[3] = p[1];
    p = __builtin_amdgcn_cvt_pk_f32_fp8(v.y, false); o[4] = p[0]; o[5] = p[1];
    p = __builtin_amdgcn_cvt_pk_f32_fp8(v.y, true);  o[6] = p[0]; o[7] = p[1];
#else
#pragma unroll
    for (int j = 0; j < 4; ++j) {
        o[j]     = f8dec((v.x >> (8 * j)) & 0xFF);
        o[j + 4] = f8dec((v.y >> (8 * j)) & 0xFF);
    }
#endif
}
// decode 8 fp8 -> 4 packed f32x2 (enables v_pk_add_f32 accumulate)
__device__ inline void dec8p(uint2 v, f32x2* o) {
#ifdef HAVE_CVT_PK_F32_FP8
    o[0] = __builtin_amdgcn_cvt_pk_f32_fp8(v.x, false);
    o[1] = __builtin_amdgcn_cvt_pk_f32_fp8(v.x, true);
    o[2] = __builtin_amdgcn_cvt_pk_f32_fp8(v.y, false);
    o[3] = __builtin_amdgcn_cvt_pk_f32_fp8(v.y, true);
#else
    float d[8]; dec8(v, d);
#pragma unroll
    for (int j = 0; j < 4; ++j) { o[j][0] = d[2 * j]; o[j][1] = d[2 * j + 1]; }
#endif
}
// encode 8 f32 -> uint2 of fp8
__device__ inline uint2 enc8(const float* d) {
    unsigned a = 0, b = 0;
#pragma unroll
    for (int j = 0; j < 4; ++j) {
        a |= ((unsigned)f8enc(d[j])) << (8 * j);
        b |= ((unsigned)f8enc(d[j + 4])) << (8 * j);
    }
    uint2 o; o.x = a; o.y = b; return o;
}

// -------- fused: x f32 -> fp8 convert + weight combine/pack --------
__global__ __launch_bounds__(256) void combo_kernel(const float* __restrict__ x,
                                                    unsigned char* __restrict__ x8,
                                                    const float* __restrict__ W1, const float* __restrict__ b1,
                                                    const float* __restrict__ Wr1, const float* __restrict__ br1,
                                                    const float* __restrict__ W2, const float* __restrict__ b2,
                                                    const float* __restrict__ Wr, const float* __restrict__ br,
                                                    unsigned short* __restrict__ Wpack, float* __restrict__ bc) {
    int bid = blockIdx.x;
    if (bid < XCONV_BLOCKS) {
        int i = bid * 256 + threadIdx.x;      // 8-elem group
        float4 v0 = ((const float4*)x)[i * 2];
        float4 v1 = ((const float4*)x)[i * 2 + 1];
        float d[8] = {v0.x, v0.y, v0.z, v0.w, v1.x, v1.y, v1.z, v1.w};
        ((uint2*)x8)[i] = enc8(d);
        return;
    }
    int idx = (bid - XCONV_BLOCKS) * 256 + threadIdx.x;   // < 3*16384
    int l = idx / 16384, rem = idx % 16384;
    int cb = rem / 2048;
    int kb = (rem / 512) % 4;
    int lane = (rem / 8) % 64;
    int j = rem % 8;
    int k = kb * 32 + (lane >> 4) * 8 + j;
    int c = cb * 16 + (lane & 15);
    int wi = k * HH + c;
    float v = (l == 0) ? 0.95f * W1[wi] + 0.05f * Wr1[wi]
                       : 0.95f * W2[(l - 1) * 16384 + wi] + 0.05f * Wr[wi];
    Wpack[idx] = f2bf(v);
    if (rem < HH) {
        bc[l * HH + rem] = (l == 0) ? 0.95f * b1[rem] + 0.05f * br1[rem]
                                    : 0.95f * b2[(l - 1) * HH + rem] + 0.05f * br[rem];
    }
}

// ---- partA: single-pass bucket partition (LDS hist -> global reserve -> scatter) ----
__global__ __launch_bounds__(256) void partA_kernel(const int* __restrict__ ei,
                                                    int* __restrict__ blen,
                                                    uint2* __restrict__ eb) {
    __shared__ int h[NBUCKET];
    int c = blockIdx.x, t = threadIdx.x;
    if (t < NBUCKET) h[t] = 0;
    __syncthreads();
    int beg = c * CE, end = min(beg + CE, NE);
    for (int e = beg + t; e < end; e += 256)
        atomicAdd(&h[ei[NE + e] / BSPAN], 1);
    __syncthreads();
    if (t < NBUCKET) h[t] = atomicAdd(&blen[t], h[t]);   // reserve; h becomes base cursor
    __syncthreads();
    for (int e = beg + t; e < end; e += 256) {
        int d = ei[NE + e];
        int s = ei[e];
        int b = d / BSPAN;
        int p = atomicAdd(&h[b], 1);
        uint2 pr; pr.x = (unsigned)d; pr.y = (unsigned)s;
        eb[(size_t)b * CAP + p] = pr;
    }
}

// ---- partB1: per-bucket node counts + global offsets (LDS scan) + dinv ----
__global__ __launch_bounds__(256) void partB1_kernel(const uint2* __restrict__ eb,
                                                     const int* __restrict__ blen,
                                                     int* __restrict__ offs,
                                                     float* __restrict__ dinv) {
    __shared__ int hcnt[BSPAN];
    __shared__ int sh[256];
    __shared__ int gbase_sh;
    int b = blockIdx.x, t = threadIdx.x;
    int lo = b * BSPAN;
    int span = min(BSPAN, NN - lo);
    if (span <= 0) return;
    for (int i = t; i < span; i += 256) hcnt[i] = 0;
    if (t == 0) {
        int g = 0;
        for (int i = 0; i < b; ++i) g += blen[i];
        gbase_sh = g;
    }
    __syncthreads();
    int len = blen[b];
    const uint2* ebb = eb + (size_t)b * CAP;
    for (int e = t; e < len; e += 256)
        atomicAdd(&hcnt[(int)ebb[e].x - lo], 1);
    __syncthreads();
    int base = t * 4;
    int v[4]; int s = 0;
#pragma unroll
    for (int j = 0; j < 4; ++j) { int i = base + j; v[j] = (i < span) ? hcnt[i] : 0; s += v[j]; }
    sh[t] = s; __syncthreads();
    for (int off = 1; off < 256; off <<= 1) {
        int x = (t >= off) ? sh[t - off] : 0; __syncthreads();
        sh[t] += x; __syncthreads();
    }
    int excl = sh[t] - s + gbase_sh;
#pragma unroll
    for (int j = 0; j < 4; ++j) {
        int i = base + j;
        if (i < span) {
            offs[lo + i] = excl;
            dinv[lo + i] = rsqrtf((float)v[j] + 1.0f);
            excl += v[j];
        }
    }
    if (b == NBUCKET - 1 && t == 0) offs[NN] = NE;
}

// ---- partB2: final CSR fill (src only); LDS cursors ----
__global__ __launch_bounds__(256) void partB2_kernel(const uint2* __restrict__ eb,
                                                     const int* __restrict__ blen,
                                                     const int* __restrict__ offs,
                                                     int* __restrict__ csrc) {
    __shared__ int lcur[BSPAN];
    int b = blockIdx.x, t = threadIdx.x;
    int lo = b * BSPAN;
    int span = min(BSPAN, NN - lo);
    if (span <= 0) return;
    for (int i = t; i < span; i += 256) lcur[i] = offs[lo + i];
    __syncthreads();
    int len = blen[b];
    const uint2* ebb = eb + (size_t)b * CAP;
    for (int e = t; e < len; e += 256) {
        uint2 pr = ebb[e];
        int p = atomicAdd(&lcur[(int)pr.x - lo], 1);
        csrc[p] = (int)pr.y;
    }
}

// ------- MFMA GEMM: t8[N,128](fp8) = rowscale(dinv) * (A8[N,128](fp8->bf16) @ Wc) -------
__global__ __launch_bounds__(256) void gemm_mfma_kernel(const unsigned char* __restrict__ A8,
                                                        const unsigned short* __restrict__ Wp,
                                                        const float* __restrict__ dinv,
                                                        unsigned char* __restrict__ out8,
                                                        int nrows) {
    __shared__ unsigned char f8s[64][128];
    int w = threadIdx.x >> 6;
    int l = threadIdx.x & 63;
    int m0 = blockIdx.x * 64 + w * 16;
    int kg = l >> 4;
    int cl = l & 15;
    int arow = m0 + cl;

    short8 a[4];
    if (arow < nrows) {
        const uint2* Ar = (const uint2*)(A8 + (size_t)arow * HH);
#pragma unroll
        for (int kb = 0; kb < 4; ++kb) {
            uint2 v = Ar[kb * 4 + kg];
            float d[8]; dec8(v, d);
            short8 t;
#pragma unroll
            for (int j = 0; j < 8; ++j) t[j] = (short)f2bf(d[j]);
            a[kb] = t;
        }
    } else {
        short8 z = {};
#pragma unroll
        for (int kb = 0; kb < 4; ++kb) a[kb] = z;
    }

    float dv[4];
#pragma unroll
    for (int r = 0; r < 4; ++r) {
        int orow = m0 + kg * 4 + r;
        dv[r] = (orow < nrows) ? dinv[orow] : 0.f;
    }

#pragma unroll
    for (int cb = 0; cb < 8; ++cb) {
        f32x4 acc = {0.f, 0.f, 0.f, 0.f};
#pragma unroll
        for (int kb = 0; kb < 4; ++kb) {
            short8 b = *(const short8*)(Wp + (size_t)(cb * 4 + kb) * 512 + l * 8);
            acc = __builtin_amdgcn_mfma_f32_16x16x32_bf16(a[kb], b, acc, 0, 0, 0);
        }
#pragma unroll
        for (int r = 0; r < 4; ++r)
            f8s[w * 16 + kg * 4 + r][cb * 16 + cl] = f8enc(acc[r] * dv[r]);
    }
    __syncthreads();
    int blk0 = blockIdx.x * 64;
    for (int u = threadIdx.x; u < 512; u += 256) {       // 64 rows x 8 x 16B
        int row = u >> 3, c16 = u & 7;
        int grow = blk0 + row;
        if (grow < nrows)
            ((uint4*)out8)[(size_t)grow * 8 + c16] = ((const uint4*)&f8s[row][0])[c16];
    }
}

// ---- aggregation: h8[n] = fp8(relu(dinv[n]*(t'[n] + sum_{s} t'[s]) + b)) ----
__global__ __launch_bounds__(256) void agg_relu_kernel(const unsigned char* __restrict__ t8,
                                                       const int* __restrict__ offs,
                                                       const int* __restrict__ csrc,
                                                       const float* __restrict__ dinv,
                                                       const float* __restrict__ bias,
                                                       unsigned char* __restrict__ hOut) {
    int n = blockIdx.x * 16 + (threadIdx.x >> 4);
    if (n >= NN) return;
    int lane = threadIdx.x & 15;          // features lane*8 .. lane*8+7
    int beg = offs[n], end = offs[n + 1];
    const uint2* g8 = (const uint2*)t8;
    f32x2 acc2[4] = {};
    f32x2 d2[4];
    int e = beg;
    for (; e + 3 < end; e += 4) {
        int s0 = csrc[e], s1 = csrc[e + 1], s2 = csrc[e + 2], s3 = csrc[e + 3];
        uint2 v0 = g8[(size_t)s0 * 16 + lane];
        uint2 v1 = g8[(size_t)s1 * 16 + lane];
        uint2 v2 = g8[(size_t)s2 * 16 + lane];
        uint2 v3 = g8[(size_t)s3 * 16 + lane];
        dec8p(v0, d2);
#pragma unroll
        for (int k = 0; k < 4; ++k) acc2[k] += d2[k];
        dec8p(v1, d2);
#pragma unroll
        for (int k = 0; k < 4; ++k) acc2[k] += d2[k];
        dec8p(v2, d2);
#pragma unroll
        for (int k = 0; k < 4; ++k) acc2[k] += d2[k];
        dec8p(v3, d2);
#pragma unroll
        for (int k = 0; k < 4; ++k) acc2[k] += d2[k];
    }
    for (; e < end; ++e) {
        uint2 v = g8[(size_t)csrc[e] * 16 + lane];
        dec8p(v, d2);
#pragma unroll
        for (int k = 0; k < 4; ++k) acc2[k] += d2[k];
    }
    {   // self term
        uint2 v = g8[(size_t)n * 16 + lane];
        dec8p(v, d2);
#pragma unroll
        for (int k = 0; k < 4; ++k) acc2[k] += d2[k];
    }
    float dn = dinv[n];
    float4 bv0 = ((const float4*)bias)[lane * 2];
    float4 bv1 = ((const float4*)bias)[lane * 2 + 1];
    float bb[8] = {bv0.x, bv0.y, bv0.z, bv0.w, bv1.x, bv1.y, bv1.z, bv1.w};
    float o[8];
#pragma unroll
    for (int j = 0; j < 8; ++j)
        o[j] = fmaxf(fmaf(acc2[j >> 1][j & 1], dn, bb[j]), 0.f);
    ((uint2*)hOut)[(size_t)n * 16 + lane] = enc8(o);
}

// -------- pooling stage 1: 16 segments/graph, partials to psum_seg (no atomics) --------
__global__ __launch_bounds__(256) void poolseg_kernel(const unsigned char* __restrict__ h8,
                                                      const int* __restrict__ batch,
                                                      float* __restrict__ psum_seg) {
    int g = blockIdx.x >> 4;
    int seg = blockIdx.x & (PSEG - 1);
    int t = threadIdx.x;
    int lo = 0, hi = NN;
    while (lo < hi) { int m = (lo + hi) >> 1; if (batch[m] < g) lo = m + 1; else hi = m; }
    int lb = lo;
    lo = 0; hi = NN;
    while (lo < hi) { int m = (lo + hi) >> 1; if (batch[m] <= g) lo = m + 1; else hi = m; }
    int ub = lo;
    int len = ub - lb;
    int b0 = lb + (int)(((long long)len * seg) / PSEG);
    int b1 = lb + (int)(((long long)len * (seg + 1)) / PSEG);

    int fg = t & 15;        // feature group
    int rg = t >> 4;        // row slot 0..15
    const uint2* gp = (const uint2*)h8;
    f32x2 acc2[4] = {};
    f32x2 d2[4];
    for (int n = b0 + rg; n < b1; n += 16) {
        uint2 v = gp[(size_t)n * 16 + fg];
        dec8p(v, d2);
#pragma unroll
        for (int k = 0; k < 4; ++k) acc2[k] += d2[k];
    }
    __shared__ float red[256][8];
#pragma unroll
    for (int j = 0; j < 8; ++j) red[t][j] = acc2[j >> 1][j & 1];
    __syncthreads();
    for (int off = 8; off >= 1; off >>= 1) {
        if (rg < off) {
#pragma unroll
            for (int j = 0; j < 8; ++j) red[t][j] += red[t + off * 16][j];
        }
        __syncthreads();
    }
    if (t < 16) {
#pragma unroll
        for (int j = 0; j < 8; ++j)
            psum_seg[((size_t)g * PSEG + seg) * HH + t * 8 + j] = red[t][j];
    }
}

// -------- pooling stage 2 + MLP + log_softmax: one block per graph --------
__global__ __launch_bounds__(128) void mlp2_kernel(const float* __restrict__ psum_seg,
                                                   const int* __restrict__ batch,
                                                   const float* __restrict__ Wl1,
                                                   const float* __restrict__ bl1,
                                                   const float* __restrict__ Wl2,
                                                   const float* __restrict__ bl2,
                                                   float* __restrict__ out) {
    __shared__ float p[128], o1[128], lg[CC];
    int g = blockIdx.x, t = threadIdx.x;
    int lo = 0, hi = NN;
    while (lo < hi) { int m = (lo + hi) >> 1; if (batch[m] < g) lo = m + 1; else hi = m; }
    int lb = lo;
    lo = 0; hi = NN;
    while (lo < hi) { int m = (lo + hi) >> 1; if (batch[m] <= g) lo = m + 1; else hi = m; }
    int len = lo - lb;
    float a = 0.f;
#pragma unroll
    for (int s = 0; s < PSEG; ++s)
        a += psum_seg[((size_t)g * PSEG + s) * HH + t];
    p[t] = a / fmaxf((float)len, 1.f);
    __syncthreads();
    float acc = bl1[t];
    for (int k = 0; k < HH; ++k) acc = fmaf(p[k], Wl1[k * HH + t], acc);
    o1[t] = fmaxf(acc, 0.f);
    __syncthreads();
    if (t < CC) {
        float a2 = bl2[t];
        for (int j = 0; j < HH; ++j) a2 = fmaf(o1[j], Wl2[j * CC + t], a2);
        lg[t] = a2;
    }
    __syncthreads();
    if (t == 0) {
        float m = lg[0];
        for (int c = 1; c < CC; ++c) m = fmaxf(m, lg[c]);
        float s = 0.f;
        for (int c = 0; c < CC; ++c) s += expf(lg[c] - m);
        float ls = logf(s);
        for (int c = 0; c < CC; ++c) out[g * CC + c] = lg[c] - m - ls;
    }
}

extern "C" void kernel_launch(void* const* d_in, const int* in_sizes, int n_in,
                              void* d_out, int out_size, void* d_ws, size_t ws_size,
                              hipStream_t stream) {
    const float* x   = (const float*)d_in[0];
    const int*   ei  = (const int*)d_in[1];
    const int*   bat = (const int*)d_in[2];
    const float* W1  = (const float*)d_in[3];
    const float* b1  = (const float*)d_in[4];
    const float* Wr1 = (const float*)d_in[5];
    const float* br1 = (const float*)d_in[6];
    const float* W2  = (const float*)d_in[7];
    const float* b2  = (const float*)d_in[8];
    const float* Wr  = (const float*)d_in[9];
    const float* br  = (const float*)d_in[10];
    const float* Wl1 = (const float*)d_in[11];
    const float* bl1 = (const float*)d_in[12];
    const float* Wl2 = (const float*)d_in[13];
    const float* bl2 = (const float*)d_in[14];
    float* out = (float*)d_out;

    // workspace carve-up (256B aligned)
    char* base = (char*)d_ws;
    size_t off = 0;
    auto alloc = [&](size_t bytes) {
        void* p = base + off;
        off += (bytes + 255) & ~(size_t)255;
        return p;
    };
    unsigned char* x8   = (unsigned char*)alloc((size_t)NN * HH);
    unsigned char* h8   = (unsigned char*)alloc((size_t)NN * HH);
    unsigned char* t8   = (unsigned char*)alloc((size_t)NN * HH);
    uint2* eb     = (uint2*)alloc((size_t)NBUCKET * CAP * 8);   // 16.8 MB
    int*   csrc   = (int*)alloc((size_t)NE * 4);
    int*   offs   = (int*)alloc((size_t)(NN + 1) * 4);
    float* dinv   = (float*)alloc((size_t)NN * 4);
    int*   blen   = (int*)alloc(NBUCKET * 4);
    unsigned short* Wpack = (unsigned short*)alloc(3 * 16384 * 2);
    float* bc     = (float*)alloc(3 * HH * 4);
    float* psum_seg = (float*)alloc((size_t)GG * PSEG * HH * 4);
    (void)ws_size; (void)in_sizes; (void)n_in; (void)out_size;

    hipMemsetAsync(blen, 0, NBUCKET * 4, stream);

    // fused input-convert + weight combine
    combo_kernel<<<XCONV_BLOCKS + 192, 256, 0, stream>>>(x, x8, W1, b1, Wr1, br1,
                                                         W2, b2, Wr, br, Wpack, bc);

    // partition: 3 kernels
    partA_kernel<<<NCHUNK, 256, 0, stream>>>(ei, blen, eb);
    partB1_kernel<<<NBUCKET, 256, 0, stream>>>(eb, blen, offs, dinv);
    partB2_kernel<<<NBUCKET, 256, 0, stream>>>(eb, blen, offs, csrc);

    const int GEMM_BLOCKS = (NN + 63) / 64;
    const int AGG_BLOCKS = (NN + 15) / 16;
    // layer 0
    gemm_mfma_kernel<<<GEMM_BLOCKS, 256, 0, stream>>>(x8, Wpack, dinv, t8, NN);
    agg_relu_kernel<<<AGG_BLOCKS, 256, 0, stream>>>(t8, offs, csrc, dinv, bc, h8);
    // layer 1
    gemm_mfma_kernel<<<GEMM_BLOCKS, 256, 0, stream>>>(h8, Wpack + 16384, dinv, t8, NN);
    agg_relu_kernel<<<AGG_BLOCKS, 256, 0, stream>>>(t8, offs, csrc, dinv, bc + HH, h8);
    // layer 2
    gemm_mfma_kernel<<<GEMM_BLOCKS, 256, 0, stream>>>(h8, Wpack + 2 * 16384, dinv, t8, NN);
    agg_relu_kernel<<<AGG_BLOCKS, 256, 0, stream>>>(t8, offs, csrc, dinv, bc + 2 * HH, h8);

    // pooling (parallel segments, no atomics) + readout
    poolseg_kernel<<<GG * PSEG, 256, 0, stream>>>(h8, bat, psum_seg);
    mlp2_kernel<<<GG, 128, 0, stream>>>(psum_seg, bat, Wl1, bl1, Wl2, bl2, out);
}

// Round 14
// 253.211 us; speedup vs baseline: 1.1165x; 1.1165x over previous
//
#include <hip/hip_runtime.h>
#include <hip/hip_bf16.h>
#include <hip/hip_fp8.h>

#define NN 100000
#define NE 1600000
#define FF 128
#define HH 128
#define CC 10
#define GG 64

#define NCHUNK 2048
#define CE 782            // ceil(NE/NCHUNK)
#define NBUCKET 128
#define BSPAN 782         // ceil(NN/NBUCKET)
#define XCONV_BLOCKS 6250 // NN*HH/8/256
#define PSEG 16

typedef __attribute__((ext_vector_type(8))) short short8;
typedef __attribute__((ext_vector_type(4))) float f32x4;
typedef __attribute__((ext_vector_type(2))) float f32x2;

__device__ inline unsigned short f2bf(float f) {
    union { float f; unsigned int i; } x;
    x.f = f;
    unsigned int r = x.i + 0x7FFF + ((x.i >> 16) & 1);  // RNE
    return (unsigned short)(r >> 16);
}
__device__ inline unsigned char f8enc(float v) {
    __hip_fp8_e4m3 q(v);
    return (unsigned char)q.__x;
}
__device__ inline float f8dec(unsigned char b) {
    __hip_fp8_e4m3 q;
    q.__x = (__hip_fp8_storage_t)b;
    return (float)q;
}

#if defined(__has_builtin)
#if __has_builtin(__builtin_amdgcn_cvt_pk_f32_fp8)
#define HAVE_CVT_PK_F32_FP8 1
#endif
#endif

// decode 8 fp8 (uint2) -> 8 f32 (scalar out)
__device__ inline void dec8(uint2 v, float* o) {
#ifdef HAVE_CVT_PK_F32_FP8
    f32x2 p;
    p = __builtin_amdgcn_cvt_pk_f32_fp8(v.x, false); o[0] = p[0]; o[1] = p[1];
    p = __builtin_amdgcn_cvt_pk_f32_fp8(v.x, true);  o[2] = p[0]; o[3] = p[1];
    p = __builtin_amdgcn_cvt_pk_f32_fp8(v.y, false); o[4] = p[0]; o[5] = p[1];
    p = __builtin_amdgcn_cvt_pk_f32_fp8(v.y, true);  o[6] = p[0]; o[7] = p[1];
#else
#pragma unroll
    for (int j = 0; j < 4; ++j) {
        o[j]     = f8dec((v.x >> (8 * j)) & 0xFF);
        o[j + 4] = f8dec((v.y >> (8 * j)) & 0xFF);
    }
#endif
}
// decode 8 fp8 -> 4 packed f32x2 (enables v_pk_add_f32 accumulate)
__device__ inline void dec8p(uint2 v, f32x2* o) {
#ifdef HAVE_CVT_PK_F32_FP8
    o[0] = __builtin_amdgcn_cvt_pk_f32_fp8(v.x, false);
    o[1] = __builtin_amdgcn_cvt_pk_f32_fp8(v.x, true);
    o[2] = __builtin_amdgcn_cvt_pk_f32_fp8(v.y, false);
    o[3] = __builtin_amdgcn_cvt_pk_f32_fp8(v.y, true);
#else
    float d[8]; dec8(v, d);
#pragma unroll
    for (int j = 0; j < 4; ++j) { o[j][0] = d[2 * j]; o[j][1] = d[2 * j + 1]; }
#endif
}
// encode 8 f32 -> uint2 of fp8
__device__ inline uint2 enc8(const float* d) {
    unsigned a = 0, b = 0;
#pragma unroll
    for (int j = 0; j < 4; ++j) {
        a |= ((unsigned)f8enc(d[j])) << (8 * j);
        b |= ((unsigned)f8enc(d[j + 4])) << (8 * j);
    }
    uint2 o; o.x = a; o.y = b; return o;
}

// -------- fused: x f32 -> fp8 convert + weight combine/pack --------
__global__ __launch_bounds__(256) void combo_kernel(const float* __restrict__ x,
                                                    unsigned char* __restrict__ x8,
                                                    const float* __restrict__ W1, const float* __restrict__ b1,
                                                    const float* __restrict__ Wr1, const float* __restrict__ br1,
                                                    const float* __restrict__ W2, const float* __restrict__ b2,
                                                    const float* __restrict__ Wr, const float* __restrict__ br,
                                                    unsigned short* __restrict__ Wpack, float* __restrict__ bc) {
    int bid = blockIdx.x;
    if (bid < XCONV_BLOCKS) {
        int i = bid * 256 + threadIdx.x;      // 8-elem group
        float4 v0 = ((const float4*)x)[i * 2];
        float4 v1 = ((const float4*)x)[i * 2 + 1];
        float d[8] = {v0.x, v0.y, v0.z, v0.w, v1.x, v1.y, v1.z, v1.w};
        ((uint2*)x8)[i] = enc8(d);
        return;
    }
    int idx = (bid - XCONV_BLOCKS) * 256 + threadIdx.x;   // < 3*16384
    int l = idx / 16384, rem = idx % 16384;
    int cb = rem / 2048;
    int kb = (rem / 512) % 4;
    int lane = (rem / 8) % 64;
    int j = rem % 8;
    int k = kb * 32 + (lane >> 4) * 8 + j;
    int c = cb * 16 + (lane & 15);
    int wi = k * HH + c;
    float v = (l == 0) ? 0.95f * W1[wi] + 0.05f * Wr1[wi]
                       : 0.95f * W2[(l - 1) * 16384 + wi] + 0.05f * Wr[wi];
    Wpack[idx] = f2bf(v);
    if (rem < HH) {
        bc[l * HH + rem] = (l == 0) ? 0.95f * b1[rem] + 0.05f * br1[rem]
                                    : 0.95f * b2[(l - 1) * HH + rem] + 0.05f * br[rem];
    }
}

// ---- A1: per-chunk per-bucket counts (LDS histogram, no global atomics) ----
__global__ __launch_bounds__(256) void partA1_kernel(const int* __restrict__ ei,
                                                     int* __restrict__ cc) {
    __shared__ int h[NBUCKET];
    int c = blockIdx.x, t = threadIdx.x;
    if (t < NBUCKET) h[t] = 0;
    __syncthreads();
    int beg = c * CE, end = min(beg + CE, NE);
    for (int e = beg + t; e < end; e += 256)
        atomicAdd(&h[ei[NE + e] / BSPAN], 1);
    __syncthreads();
    if (t < NBUCKET) cc[c * NBUCKET + t] = h[t];
}

// ---- A2: per-bucket exclusive scan over 2048 chunks (in-place on cc); tot[b] out ----
__global__ __launch_bounds__(256) void partA2_kernel(int* __restrict__ cc,
                                                     int* __restrict__ tot) {
    __shared__ int sh[256];
    int b = blockIdx.x, t = threadIdx.x;
    int v[8]; int s = 0;
#pragma unroll
    for (int i = 0; i < 8; ++i) { v[i] = cc[(t * 8 + i) * NBUCKET + b]; s += v[i]; }
    sh[t] = s; __syncthreads();
    for (int off = 1; off < 256; off <<= 1) {
        int x = (t >= off) ? sh[t - off] : 0; __syncthreads();
        sh[t] += x; __syncthreads();
    }
    int excl = sh[t] - s;
#pragma unroll
    for (int i = 0; i < 8; ++i) {
        cc[(t * 8 + i) * NBUCKET + b] = excl;
        excl += v[i];
    }
    if (t == 255) tot[b] = sh[255];
}

// ---- A3: scatter packed (dst,src) into COMPACT bucket-partitioned eb; LDS cursors ----
// Bucket bases computed in-LDS from tot (scan over 128), so no scanB kernel.
__global__ __launch_bounds__(256) void partA3_kernel(const int* __restrict__ ei,
                                                     const int* __restrict__ cc,
                                                     const int* __restrict__ tot,
                                                     uint2* __restrict__ eb) {
    __shared__ int stot[NBUCKET];
    __shared__ int cur[NBUCKET];
    int c = blockIdx.x, t = threadIdx.x;
    if (t < NBUCKET) stot[t] = tot[t];
    __syncthreads();
    for (int off = 1; off < NBUCKET; off <<= 1) {
        int x = (t < NBUCKET && t >= off) ? stot[t - off] : 0;
        __syncthreads();
        if (t < NBUCKET) stot[t] += x;
        __syncthreads();
    }
    if (t < NBUCKET) cur[t] = (stot[t] - tot[t]) + cc[c * NBUCKET + t];
    __syncthreads();
    int beg = c * CE, end = min(beg + CE, NE);
    for (int e = beg + t; e < end; e += 256) {
        int d = ei[NE + e];
        int s = ei[e];
        int p = atomicAdd(&cur[d / BSPAN], 1);
        uint2 pr; pr.x = (unsigned)d; pr.y = (unsigned)s;
        eb[p] = pr;
    }
}

// ---- B1: per-bucket node counts + global offsets (LDS scan) + dinv ----
// gbase = sum(tot[0..b)) == bucket's edge base in compact eb.
__global__ __launch_bounds__(256) void partB1_kernel(const uint2* __restrict__ eb,
                                                     const int* __restrict__ tot,
                                                     int* __restrict__ offs,
                                                     float* __restrict__ dinv) {
    __shared__ int hcnt[BSPAN];
    __shared__ int sh[256];
    __shared__ int gbase_sh;
    int b = blockIdx.x, t = threadIdx.x;
    int lo = b * BSPAN;
    int span = min(BSPAN, NN - lo);
    if (span <= 0) return;
    for (int i = t; i < span; i += 256) hcnt[i] = 0;
    if (t == 0) {
        int g = 0;
        for (int i = 0; i < b; ++i) g += tot[i];
        gbase_sh = g;
    }
    __syncthreads();
    int gbase = gbase_sh;
    int len = tot[b];
    const uint2* ebb = eb + (size_t)gbase;
    for (int e = t; e < len; e += 256)
        atomicAdd(&hcnt[(int)ebb[e].x - lo], 1);
    __syncthreads();
    int base = t * 4;
    int v[4]; int s = 0;
#pragma unroll
    for (int j = 0; j < 4; ++j) { int i = base + j; v[j] = (i < span) ? hcnt[i] : 0; s += v[j]; }
    sh[t] = s; __syncthreads();
    for (int off = 1; off < 256; off <<= 1) {
        int x = (t >= off) ? sh[t - off] : 0; __syncthreads();
        sh[t] += x; __syncthreads();
    }
    int excl = sh[t] - s + gbase;
#pragma unroll
    for (int j = 0; j < 4; ++j) {
        int i = base + j;
        if (i < span) {
            offs[lo + i] = excl;
            dinv[lo + i] = rsqrtf((float)v[j] + 1.0f);
            excl += v[j];
        }
    }
    if (b == NBUCKET - 1 && t == 0) offs[NN] = NE;
}

// ---- B2: final CSR fill (src only); bucket edge range recovered from offs ----
__global__ __launch_bounds__(256) void partB2_kernel(const uint2* __restrict__ eb,
                                                     const int* __restrict__ offs,
                                                     int* __restrict__ csrc) {
    __shared__ int lcur[BSPAN];
    int b = blockIdx.x, t = threadIdx.x;
    int lo = b * BSPAN;
    int span = min(BSPAN, NN - lo);
    if (span <= 0) return;
    for (int i = t; i < span; i += 256) lcur[i] = offs[lo + i];
    __syncthreads();
    int ebeg = offs[lo];
    int eend = offs[min(lo + span, NN)];
    for (int e = ebeg + t; e < eend; e += 256) {
        uint2 pr = eb[e];
        int p = atomicAdd(&lcur[(int)pr.x - lo], 1);
        csrc[p] = (int)pr.y;
    }
}

// ------- MFMA GEMM: t8[N,128](fp8) = rowscale(dinv) * (A8[N,128](fp8->bf16) @ Wc) -------
__global__ __launch_bounds__(256) void gemm_mfma_kernel(const unsigned char* __restrict__ A8,
                                                        const unsigned short* __restrict__ Wp,
                                                        const float* __restrict__ dinv,
                                                        unsigned char* __restrict__ out8,
                                                        int nrows) {
    __shared__ unsigned char f8s[64][128];
    int w = threadIdx.x >> 6;
    int l = threadIdx.x & 63;
    int m0 = blockIdx.x * 64 + w * 16;
    int kg = l >> 4;
    int cl = l & 15;
    int arow = m0 + cl;

    short8 a[4];
    if (arow < nrows) {
        const uint2* Ar = (const uint2*)(A8 + (size_t)arow * HH);
#pragma unroll
        for (int kb = 0; kb < 4; ++kb) {
            uint2 v = Ar[kb * 4 + kg];
            float d[8]; dec8(v, d);
            short8 t;
#pragma unroll
            for (int j = 0; j < 8; ++j) t[j] = (short)f2bf(d[j]);
            a[kb] = t;
        }
    } else {
        short8 z = {};
#pragma unroll
        for (int kb = 0; kb < 4; ++kb) a[kb] = z;
    }

    float dv[4];
#pragma unroll
    for (int r = 0; r < 4; ++r) {
        int orow = m0 + kg * 4 + r;
        dv[r] = (orow < nrows) ? dinv[orow] : 0.f;
    }

#pragma unroll
    for (int cb = 0; cb < 8; ++cb) {
        f32x4 acc = {0.f, 0.f, 0.f, 0.f};
#pragma unroll
        for (int kb = 0; kb < 4; ++kb) {
            short8 b = *(const short8*)(Wp + (size_t)(cb * 4 + kb) * 512 + l * 8);
            acc = __builtin_amdgcn_mfma_f32_16x16x32_bf16(a[kb], b, acc, 0, 0, 0);
        }
#pragma unroll
        for (int r = 0; r < 4; ++r)
            f8s[w * 16 + kg * 4 + r][cb * 16 + cl] = f8enc(acc[r] * dv[r]);
    }
    __syncthreads();
    int blk0 = blockIdx.x * 64;
    for (int u = threadIdx.x; u < 512; u += 256) {       // 64 rows x 8 x 16B
        int row = u >> 3, c16 = u & 7;
        int grow = blk0 + row;
        if (grow < nrows)
            ((uint4*)out8)[(size_t)grow * 8 + c16] = ((const uint4*)&f8s[row][0])[c16];
    }
}

// ---- aggregation: h8[n] = fp8(relu(dinv[n]*(t'[n] + sum_{s} t'[s]) + b)) ----
__global__ __launch_bounds__(256) void agg_relu_kernel(const unsigned char* __restrict__ t8,
                                                       const int* __restrict__ offs,
                                                       const int* __restrict__ csrc,
                                                       const float* __restrict__ dinv,
                                                       const float* __restrict__ bias,
                                                       unsigned char* __restrict__ hOut) {
    int n = blockIdx.x * 16 + (threadIdx.x >> 4);
    if (n >= NN) return;
    int lane = threadIdx.x & 15;          // features lane*8 .. lane*8+7
    int beg = offs[n], end = offs[n + 1];
    const uint2* g8 = (const uint2*)t8;
    f32x2 acc2[4] = {};
    f32x2 d2[4];
    int e = beg;
    for (; e + 3 < end; e += 4) {
        int s0 = csrc[e], s1 = csrc[e + 1], s2 = csrc[e + 2], s3 = csrc[e + 3];
        uint2 v0 = g8[(size_t)s0 * 16 + lane];
        uint2 v1 = g8[(size_t)s1 * 16 + lane];
        uint2 v2 = g8[(size_t)s2 * 16 + lane];
        uint2 v3 = g8[(size_t)s3 * 16 + lane];
        dec8p(v0, d2);
#pragma unroll
        for (int k = 0; k < 4; ++k) acc2[k] += d2[k];
        dec8p(v1, d2);
#pragma unroll
        for (int k = 0; k < 4; ++k) acc2[k] += d2[k];
        dec8p(v2, d2);
#pragma unroll
        for (int k = 0; k < 4; ++k) acc2[k] += d2[k];
        dec8p(v3, d2);
#pragma unroll
        for (int k = 0; k < 4; ++k) acc2[k] += d2[k];
    }
    for (; e < end; ++e) {
        uint2 v = g8[(size_t)csrc[e] * 16 + lane];
        dec8p(v, d2);
#pragma unroll
        for (int k = 0; k < 4; ++k) acc2[k] += d2[k];
    }
    {   // self term
        uint2 v = g8[(size_t)n * 16 + lane];
        dec8p(v, d2);
#pragma unroll
        for (int k = 0; k < 4; ++k) acc2[k] += d2[k];
    }
    float dn = dinv[n];
    float4 bv0 = ((const float4*)bias)[lane * 2];
    float4 bv1 = ((const float4*)bias)[lane * 2 + 1];
    float bb[8] = {bv0.x, bv0.y, bv0.z, bv0.w, bv1.x, bv1.y, bv1.z, bv1.w};
    float o[8];
#pragma unroll
    for (int j = 0; j < 8; ++j)
        o[j] = fmaxf(fmaf(acc2[j >> 1][j & 1], dn, bb[j]), 0.f);
    ((uint2*)hOut)[(size_t)n * 16 + lane] = enc8(o);
}

// -------- pooling stage 1: 16 segments/graph, partials to psum_seg (no atomics) --------
__global__ __launch_bounds__(256) void poolseg_kernel(const unsigned char* __restrict__ h8,
                                                      const int* __restrict__ batch,
                                                      float* __restrict__ psum_seg) {
    int g = blockIdx.x >> 4;
    int seg = blockIdx.x & (PSEG - 1);
    int t = threadIdx.x;
    int lo = 0, hi = NN;
    while (lo < hi) { int m = (lo + hi) >> 1; if (batch[m] < g) lo = m + 1; else hi = m; }
    int lb = lo;
    lo = 0; hi = NN;
    while (lo < hi) { int m = (lo + hi) >> 1; if (batch[m] <= g) lo = m + 1; else hi = m; }
    int ub = lo;
    int len = ub - lb;
    int b0 = lb + (int)(((long long)len * seg) / PSEG);
    int b1 = lb + (int)(((long long)len * (seg + 1)) / PSEG);

    int fg = t & 15;        // feature group
    int rg = t >> 4;        // row slot 0..15
    const uint2* gp = (const uint2*)h8;
    f32x2 acc2[4] = {};
    f32x2 d2[4];
    for (int n = b0 + rg; n < b1; n += 16) {
        uint2 v = gp[(size_t)n * 16 + fg];
        dec8p(v, d2);
#pragma unroll
        for (int k = 0; k < 4; ++k) acc2[k] += d2[k];
    }
    __shared__ float red[256][8];
#pragma unroll
    for (int j = 0; j < 8; ++j) red[t][j] = acc2[j >> 1][j & 1];
    __syncthreads();
    for (int off = 8; off >= 1; off >>= 1) {
        if (rg < off) {
#pragma unroll
            for (int j = 0; j < 8; ++j) red[t][j] += red[t + off * 16][j];
        }
        __syncthreads();
    }
    if (t < 16) {
#pragma unroll
        for (int j = 0; j < 8; ++j)
            psum_seg[((size_t)g * PSEG + seg) * HH + t * 8 + j] = red[t][j];
    }
}

// -------- pooling stage 2 + MLP + log_softmax: one block per graph --------
__global__ __launch_bounds__(128) void mlp2_kernel(const float* __restrict__ psum_seg,
                                                   const int* __restrict__ batch,
                                                   const float* __restrict__ Wl1,
                                                   const float* __restrict__ bl1,
                                                   const float* __restrict__ Wl2,
                                                   const float* __restrict__ bl2,
                                                   float* __restrict__ out) {
    __shared__ float p[128], o1[128], lg[CC];
    int g = blockIdx.x, t = threadIdx.x;
    int lo = 0, hi = NN;
    while (lo < hi) { int m = (lo + hi) >> 1; if (batch[m] < g) lo = m + 1; else hi = m; }
    int lb = lo;
    lo = 0; hi = NN;
    while (lo < hi) { int m = (lo + hi) >> 1; if (batch[m] <= g) lo = m + 1; else hi = m; }
    int len = lo - lb;
    float a = 0.f;
#pragma unroll
    for (int s = 0; s < PSEG; ++s)
        a += psum_seg[((size_t)g * PSEG + s) * HH + t];
    p[t] = a / fmaxf((float)len, 1.f);
    __syncthreads();
    float acc = bl1[t];
    for (int k = 0; k < HH; ++k) acc = fmaf(p[k], Wl1[k * HH + t], acc);
    o1[t] = fmaxf(acc, 0.f);
    __syncthreads();
    if (t < CC) {
        float a2 = bl2[t];
        for (int j = 0; j < HH; ++j) a2 = fmaf(o1[j], Wl2[j * CC + t], a2);
        lg[t] = a2;
    }
    __syncthreads();
    if (t == 0) {
        float m = lg[0];
        for (int c = 1; c < CC; ++c) m = fmaxf(m, lg[c]);
        float s = 0.f;
        for (int c = 0; c < CC; ++c) s += expf(lg[c] - m);
        float ls = logf(s);
        for (int c = 0; c < CC; ++c) out[g * CC + c] = lg[c] - m - ls;
    }
}

extern "C" void kernel_launch(void* const* d_in, const int* in_sizes, int n_in,
                              void* d_out, int out_size, void* d_ws, size_t ws_size,
                              hipStream_t stream) {
    const float* x   = (const float*)d_in[0];
    const int*   ei  = (const int*)d_in[1];
    const int*   bat = (const int*)d_in[2];
    const float* W1  = (const float*)d_in[3];
    const float* b1  = (const float*)d_in[4];
    const float* Wr1 = (const float*)d_in[5];
    const float* br1 = (const float*)d_in[6];
    const float* W2  = (const float*)d_in[7];
    const float* b2  = (const float*)d_in[8];
    const float* Wr  = (const float*)d_in[9];
    const float* br  = (const float*)d_in[10];
    const float* Wl1 = (const float*)d_in[11];
    const float* bl1 = (const float*)d_in[12];
    const float* Wl2 = (const float*)d_in[13];
    const float* bl2 = (const float*)d_in[14];
    float* out = (float*)d_out;

    // workspace carve-up (256B aligned)
    char* base = (char*)d_ws;
    size_t off = 0;
    auto alloc = [&](size_t bytes) {
        void* p = base + off;
        off += (bytes + 255) & ~(size_t)255;
        return p;
    };
    unsigned char* x8   = (unsigned char*)alloc((size_t)NN * HH);
    unsigned char* h8   = (unsigned char*)alloc((size_t)NN * HH);
    unsigned char* t8   = (unsigned char*)alloc((size_t)NN * HH);
    uint2* eb     = (uint2*)alloc((size_t)NE * 8);              // compact, 12.8 MB
    int*   cc     = (int*)alloc((size_t)NCHUNK * NBUCKET * 4);  // 1 MB
    int*   csrc   = (int*)alloc((size_t)NE * 4);
    int*   offs   = (int*)alloc((size_t)(NN + 1) * 4);
    float* dinv   = (float*)alloc((size_t)NN * 4);
    int*   tot    = (int*)alloc(NBUCKET * 4);
    unsigned short* Wpack = (unsigned short*)alloc(3 * 16384 * 2);
    float* bc     = (float*)alloc(3 * HH * 4);
    float* psum_seg = (float*)alloc((size_t)GG * PSEG * HH * 4);
    (void)ws_size; (void)in_sizes; (void)n_in; (void)out_size;

    // fused input-convert + weight combine
    combo_kernel<<<XCONV_BLOCKS + 192, 256, 0, stream>>>(x, x8, W1, b1, Wr1, br1,
                                                         W2, b2, Wr, br, Wpack, bc);

    // deterministic partition: 5 kernels, no global atomics
    partA1_kernel<<<NCHUNK, 256, 0, stream>>>(ei, cc);
    partA2_kernel<<<NBUCKET, 256, 0, stream>>>(cc, tot);
    partA3_kernel<<<NCHUNK, 256, 0, stream>>>(ei, cc, tot, eb);
    partB1_kernel<<<NBUCKET, 256, 0, stream>>>(eb, tot, offs, dinv);
    partB2_kernel<<<NBUCKET, 256, 0, stream>>>(eb, offs, csrc);

    const int GEMM_BLOCKS = (NN + 63) / 64;
    const int AGG_BLOCKS = (NN + 15) / 16;
    // layer 0
    gemm_mfma_kernel<<<GEMM_BLOCKS, 256, 0, stream>>>(x8, Wpack, dinv, t8, NN);
    agg_relu_kernel<<<AGG_BLOCKS, 256, 0, stream>>>(t8, offs, csrc, dinv, bc, h8);
    // layer 1
    gemm_mfma_kernel<<<GEMM_BLOCKS, 256, 0, stream>>>(h8, Wpack + 16384, dinv, t8, NN);
    agg_relu_kernel<<<AGG_BLOCKS, 256, 0, stream>>>(t8, offs, csrc, dinv, bc + HH, h8);
    // layer 2
    gemm_mfma_kernel<<<GEMM_BLOCKS, 256, 0, stream>>>(h8, Wpack + 2 * 16384, dinv, t8, NN);
    agg_relu_kernel<<<AGG_BLOCKS, 256, 0, stream>>>(t8, offs, csrc, dinv, bc + 2 * HH, h8);

    // pooling (parallel segments, no atomics) + readout
    poolseg_kernel<<<GG * PSEG, 256, 0, stream>>>(h8, bat, psum_seg);
    mlp2_kernel<<<GG, 128, 0, stream>>>(psum_seg, bat, Wl1, bl1, Wl2, bl2, out);
}

// Round 15
// 247.656 us; speedup vs baseline: 1.1416x; 1.0224x over previous
//
#include <hip/hip_runtime.h>
#include <hip/hip_bf16.h>
#include <hip/hip_fp8.h>

#define NN 100000
#define NE 1600000
#define FF 128
#define HH 128
#define CC 10
#define GG 64

#define NCHUNK 2048
#define CE 782            // ceil(NE/NCHUNK)
#define NBUCKET 128
#define BSPAN 782         // ceil(NN/NBUCKET)
#define XCONV_BLOCKS 6250 // NN*HH/8/256
#define PSEG 16
#define SRCBITS 17        // NN < 131072

typedef __attribute__((ext_vector_type(8))) short short8;
typedef __attribute__((ext_vector_type(4))) float f32x4;
typedef __attribute__((ext_vector_type(2))) float f32x2;

__device__ inline unsigned short f2bf(float f) {
    union { float f; unsigned int i; } x;
    x.f = f;
    unsigned int r = x.i + 0x7FFF + ((x.i >> 16) & 1);  // RNE
    return (unsigned short)(r >> 16);
}
__device__ inline unsigned char f8enc_sw(float v) {
    __hip_fp8_e4m3 q(v);
    return (unsigned char)q.__x;
}
__device__ inline float f8dec(unsigned char b) {
    __hip_fp8_e4m3 q;
    q.__x = (__hip_fp8_storage_t)b;
    return (float)q;
}

#if defined(__has_builtin)
#if __has_builtin(__builtin_amdgcn_cvt_pk_f32_fp8)
#define HAVE_CVT_PK_F32_FP8 1
#endif
#if __has_builtin(__builtin_amdgcn_cvt_pk_fp8_f32)
#define HAVE_CVT_PK_FP8 1
#endif
#endif

// decode 8 fp8 (uint2) -> 8 f32 (scalar out)
__device__ inline void dec8(uint2 v, float* o) {
#ifdef HAVE_CVT_PK_F32_FP8
    f32x2 p;
    p = __builtin_amdgcn_cvt_pk_f32_fp8(v.x, false); o[0] = p[0]; o[1] = p[1];
    p = __builtin_amdgcn_cvt_pk_f32_fp8(v.x, true);  o[2] = p[0]; o[3] = p[1];
    p = __builtin_amdgcn_cvt_pk_f32_fp8(v.y, false); o[4] = p[0]; o[5] = p[1];
    p = __builtin_amdgcn_cvt_pk_f32_fp8(v.y, true);  o[6] = p[0]; o[7] = p[1];
#else
#pragma unroll
    for (int j = 0; j < 4; ++j) {
        o[j]     = f8dec((v.x >> (8 * j)) & 0xFF);
        o[j + 4] = f8dec((v.y >> (8 * j)) & 0xFF);
    }
#endif
}
// decode 8 fp8 -> 4 packed f32x2 (enables v_pk_add_f32 accumulate)
__device__ inline void dec8p(uint2 v, f32x2* o) {
#ifdef HAVE_CVT_PK_F32_FP8
    o[0] = __builtin_amdgcn_cvt_pk_f32_fp8(v.x, false);
    o[1] = __builtin_amdgcn_cvt_pk_f32_fp8(v.x, true);
    o[2] = __builtin_amdgcn_cvt_pk_f32_fp8(v.y, false);
    o[3] = __builtin_amdgcn_cvt_pk_f32_fp8(v.y, true);
#else
    float d[8]; dec8(v, d);
#pragma unroll
    for (int j = 0; j < 4; ++j) { o[j][0] = d[2 * j]; o[j][1] = d[2 * j + 1]; }
#endif
}
// encode 4 f32 -> packed fp8 dword (HW v_cvt_pk_fp8_f32 when available)
__device__ inline unsigned enc_pk4(float a, float b, float c, float d) {
#ifdef HAVE_CVT_PK_FP8
    int w = __builtin_amdgcn_cvt_pk_fp8_f32(a, b, 0, false);
    w = __builtin_amdgcn_cvt_pk_fp8_f32(c, d, w, true);
    return (unsigned)w;
#else
    return (unsigned)f8enc_sw(a) | ((unsigned)f8enc_sw(b) << 8) |
           ((unsigned)f8enc_sw(c) << 16) | ((unsigned)f8enc_sw(d) << 24);
#endif
}
__device__ inline unsigned char f8enc1(float v) {
#ifdef HAVE_CVT_PK_FP8
    return (unsigned char)(__builtin_amdgcn_cvt_pk_fp8_f32(v, v, 0, false) & 0xFF);
#else
    return f8enc_sw(v);
#endif
}
// encode 8 f32 -> uint2 of fp8
__device__ inline uint2 enc8(const float* d) {
    uint2 o;
    o.x = enc_pk4(d[0], d[1], d[2], d[3]);
    o.y = enc_pk4(d[4], d[5], d[6], d[7]);
    return o;
}

// -------- fused: x f32 -> fp8 convert + weight combine/pack --------
__global__ __launch_bounds__(256) void combo_kernel(const float* __restrict__ x,
                                                    unsigned char* __restrict__ x8,
                                                    const float* __restrict__ W1, const float* __restrict__ b1,
                                                    const float* __restrict__ Wr1, const float* __restrict__ br1,
                                                    const float* __restrict__ W2, const float* __restrict__ b2,
                                                    const float* __restrict__ Wr, const float* __restrict__ br,
                                                    unsigned short* __restrict__ Wpack, float* __restrict__ bc) {
    int bid = blockIdx.x;
    if (bid < XCONV_BLOCKS) {
        int i = bid * 256 + threadIdx.x;      // 8-elem group
        float4 v0 = ((const float4*)x)[i * 2];
        float4 v1 = ((const float4*)x)[i * 2 + 1];
        float d[8] = {v0.x, v0.y, v0.z, v0.w, v1.x, v1.y, v1.z, v1.w};
        ((uint2*)x8)[i] = enc8(d);
        return;
    }
    int idx = (bid - XCONV_BLOCKS) * 256 + threadIdx.x;   // < 3*16384
    int l = idx / 16384, rem = idx % 16384;
    int cb = rem / 2048;
    int kb = (rem / 512) % 4;
    int lane = (rem / 8) % 64;
    int j = rem % 8;
    int k = kb * 32 + (lane >> 4) * 8 + j;
    int c = cb * 16 + (lane & 15);
    int wi = k * HH + c;
    float v = (l == 0) ? 0.95f * W1[wi] + 0.05f * Wr1[wi]
                       : 0.95f * W2[(l - 1) * 16384 + wi] + 0.05f * Wr[wi];
    Wpack[idx] = f2bf(v);
    if (rem < HH) {
        bc[l * HH + rem] = (l == 0) ? 0.95f * b1[rem] + 0.05f * br1[rem]
                                    : 0.95f * b2[(l - 1) * HH + rem] + 0.05f * br[rem];
    }
}

// ---- A1: per-chunk per-bucket counts (LDS histogram, no global atomics) ----
__global__ __launch_bounds__(256) void partA1_kernel(const int* __restrict__ ei,
                                                     int* __restrict__ cc) {
    __shared__ int h[NBUCKET];
    int c = blockIdx.x, t = threadIdx.x;
    if (t < NBUCKET) h[t] = 0;
    __syncthreads();
    int beg = c * CE, end = min(beg + CE, NE);
    for (int e = beg + t; e < end; e += 256)
        atomicAdd(&h[ei[NE + e] / BSPAN], 1);
    __syncthreads();
    if (t < NBUCKET) cc[c * NBUCKET + t] = h[t];
}

// ---- A2: per-bucket exclusive scan over 2048 chunks (in-place on cc); tot[b] out ----
__global__ __launch_bounds__(256) void partA2_kernel(int* __restrict__ cc,
                                                     int* __restrict__ tot) {
    __shared__ int sh[256];
    int b = blockIdx.x, t = threadIdx.x;
    int v[8]; int s = 0;
#pragma unroll
    for (int i = 0; i < 8; ++i) { v[i] = cc[(t * 8 + i) * NBUCKET + b]; s += v[i]; }
    sh[t] = s; __syncthreads();
    for (int off = 1; off < 256; off <<= 1) {
        int x = (t >= off) ? sh[t - off] : 0; __syncthreads();
        sh[t] += x; __syncthreads();
    }
    int excl = sh[t] - s;
#pragma unroll
    for (int i = 0; i < 8; ++i) {
        cc[(t * 8 + i) * NBUCKET + b] = excl;
        excl += v[i];
    }
    if (t == 255) tot[b] = sh[255];
}

// ---- A3: scatter packed (local_dst<<17 | src) into COMPACT bucketed eb32 ----
__global__ __launch_bounds__(256) void partA3_kernel(const int* __restrict__ ei,
                                                     const int* __restrict__ cc,
                                                     const int* __restrict__ tot,
                                                     unsigned* __restrict__ eb32) {
    __shared__ int stot[NBUCKET];
    __shared__ int cur[NBUCKET];
    int c = blockIdx.x, t = threadIdx.x;
    if (t < NBUCKET) stot[t] = tot[t];
    __syncthreads();
    for (int off = 1; off < NBUCKET; off <<= 1) {
        int x = (t < NBUCKET && t >= off) ? stot[t - off] : 0;
        __syncthreads();
        if (t < NBUCKET) stot[t] += x;
        __syncthreads();
    }
    if (t < NBUCKET) cur[t] = (stot[t] - tot[t]) + cc[c * NBUCKET + t];
    __syncthreads();
    int beg = c * CE, end = min(beg + CE, NE);
    for (int e = beg + t; e < end; e += 256) {
        int d = ei[NE + e];
        int s = ei[e];
        int b = d / BSPAN;
        int ld = d - b * BSPAN;
        int p = atomicAdd(&cur[b], 1);
        eb32[p] = (unsigned)s | ((unsigned)ld << SRCBITS);
    }
}

// ---- B (fused): bucket hist -> offs + dinv -> CSR scatter (eb slice L2-hot) ----
__global__ __launch_bounds__(256) void partB_kernel(const unsigned* __restrict__ eb32,
                                                    const int* __restrict__ tot,
                                                    int* __restrict__ offs,
                                                    float* __restrict__ dinv,
                                                    int* __restrict__ csrc) {
    __shared__ int hcnt[BSPAN];
    __shared__ int lcur[BSPAN];
    __shared__ int sh[256];
    __shared__ int gbase_sh;
    int b = blockIdx.x, t = threadIdx.x;
    int lo = b * BSPAN;
    int span = min(BSPAN, NN - lo);
    if (span <= 0) return;
    for (int i = t; i < span; i += 256) hcnt[i] = 0;
    if (t == 0) {
        int g = 0;
        for (int i = 0; i < b; ++i) g += tot[i];
        gbase_sh = g;
    }
    __syncthreads();
    int gbase = gbase_sh;
    int len = tot[b];
    const unsigned* ebb = eb32 + (size_t)gbase;
    for (int e = t; e < len; e += 256)
        atomicAdd(&hcnt[ebb[e] >> SRCBITS], 1);
    __syncthreads();
    int base = t * 4;
    int v[4]; int s = 0;
#pragma unroll
    for (int j = 0; j < 4; ++j) { int i = base + j; v[j] = (i < span) ? hcnt[i] : 0; s += v[j]; }
    sh[t] = s; __syncthreads();
    for (int off = 1; off < 256; off <<= 1) {
        int x = (t >= off) ? sh[t - off] : 0; __syncthreads();
        sh[t] += x; __syncthreads();
    }
    int excl = sh[t] - s + gbase;
#pragma unroll
    for (int j = 0; j < 4; ++j) {
        int i = base + j;
        if (i < span) {
            offs[lo + i] = excl;
            lcur[i] = excl;
            dinv[lo + i] = rsqrtf((float)v[j] + 1.0f);
            excl += v[j];
        }
    }
    if (b == NBUCKET - 1 && t == 0) offs[NN] = NE;
    __syncthreads();
    // CSR scatter; ebb slice (~100KB) is L2-resident from the histogram pass
    for (int e = t; e < len; e += 256) {
        unsigned pr = ebb[e];
        int p = atomicAdd(&lcur[pr >> SRCBITS], 1);
        csrc[p] = (int)(pr & ((1u << SRCBITS) - 1));
    }
}

// ------- MFMA GEMM: t8[N,128](fp8) = rowscale(dinv) * (A8[N,128](fp8->bf16) @ Wc) -------
__global__ __launch_bounds__(256) void gemm_mfma_kernel(const unsigned char* __restrict__ A8,
                                                        const unsigned short* __restrict__ Wp,
                                                        const float* __restrict__ dinv,
                                                        unsigned char* __restrict__ out8,
                                                        int nrows) {
    __shared__ unsigned char f8s[64][128];
    int w = threadIdx.x >> 6;
    int l = threadIdx.x & 63;
    int m0 = blockIdx.x * 64 + w * 16;
    int kg = l >> 4;
    int cl = l & 15;
    int arow = m0 + cl;

    short8 a[4];
    if (arow < nrows) {
        const uint2* Ar = (const uint2*)(A8 + (size_t)arow * HH);
#pragma unroll
        for (int kb = 0; kb < 4; ++kb) {
            uint2 v = Ar[kb * 4 + kg];
            float d[8]; dec8(v, d);
            short8 t;
#pragma unroll
            for (int j = 0; j < 8; ++j) t[j] = (short)f2bf(d[j]);
            a[kb] = t;
        }
    } else {
        short8 z = {};
#pragma unroll
        for (int kb = 0; kb < 4; ++kb) a[kb] = z;
    }

    float dv[4];
#pragma unroll
    for (int r = 0; r < 4; ++r) {
        int orow = m0 + kg * 4 + r;
        dv[r] = (orow < nrows) ? dinv[orow] : 0.f;
    }

#pragma unroll
    for (int cb = 0; cb < 8; ++cb) {
        f32x4 acc = {0.f, 0.f, 0.f, 0.f};
#pragma unroll
        for (int kb = 0; kb < 4; ++kb) {
            short8 b = *(const short8*)(Wp + (size_t)(cb * 4 + kb) * 512 + l * 8);
            acc = __builtin_amdgcn_mfma_f32_16x16x32_bf16(a[kb], b, acc, 0, 0, 0);
        }
#pragma unroll
        for (int r = 0; r < 4; ++r)
            f8s[w * 16 + kg * 4 + r][cb * 16 + cl] = f8enc1(acc[r] * dv[r]);
    }
    __syncthreads();
    int blk0 = blockIdx.x * 64;
    for (int u = threadIdx.x; u < 512; u += 256) {       // 64 rows x 8 x 16B
        int row = u >> 3, c16 = u & 7;
        int grow = blk0 + row;
        if (grow < nrows)
            ((uint4*)out8)[(size_t)grow * 8 + c16] = ((const uint4*)&f8s[row][0])[c16];
    }
}

// ---- aggregation: 8 lanes/node, uint4 row loads; h8[n]=fp8(relu(dinv*(sum)+b)) ----
__global__ __launch_bounds__(256) void agg_relu_kernel(const unsigned char* __restrict__ t8,
                                                       const int* __restrict__ offs,
                                                       const int* __restrict__ csrc,
                                                       const float* __restrict__ dinv,
                                                       const float* __restrict__ bias,
                                                       unsigned char* __restrict__ hOut) {
    int n = blockIdx.x * 32 + (threadIdx.x >> 3);
    if (n >= NN) return;
    int lane = threadIdx.x & 7;           // features lane*16 .. lane*16+15
    int beg = offs[n], end = offs[n + 1];
    const uint4* g16 = (const uint4*)t8;  // row = 8 uint4 (128 fp8)
    f32x2 acc2[8] = {};
    f32x2 d2[4];
    int e = beg;
    for (; e + 3 < end; e += 4) {
        int s0 = csrc[e], s1 = csrc[e + 1], s2 = csrc[e + 2], s3 = csrc[e + 3];
        uint4 v0 = g16[(size_t)s0 * 8 + lane];
        uint4 v1 = g16[(size_t)s1 * 8 + lane];
        uint4 v2 = g16[(size_t)s2 * 8 + lane];
        uint4 v3 = g16[(size_t)s3 * 8 + lane];
        uint2 a, b;
        a.x = v0.x; a.y = v0.y; b.x = v0.z; b.y = v0.w;
        dec8p(a, d2);
#pragma unroll
        for (int k = 0; k < 4; ++k) acc2[k] += d2[k];
        dec8p(b, d2);
#pragma unroll
        for (int k = 0; k < 4; ++k) acc2[k + 4] += d2[k];
        a.x = v1.x; a.y = v1.y; b.x = v1.z; b.y = v1.w;
        dec8p(a, d2);
#pragma unroll
        for (int k = 0; k < 4; ++k) acc2[k] += d2[k];
        dec8p(b, d2);
#pragma unroll
        for (int k = 0; k < 4; ++k) acc2[k + 4] += d2[k];
        a.x = v2.x; a.y = v2.y; b.x = v2.z; b.y = v2.w;
        dec8p(a, d2);
#pragma unroll
        for (int k = 0; k < 4; ++k) acc2[k] += d2[k];
        dec8p(b, d2);
#pragma unroll
        for (int k = 0; k < 4; ++k) acc2[k + 4] += d2[k];
        a.x = v3.x; a.y = v3.y; b.x = v3.z; b.y = v3.w;
        dec8p(a, d2);
#pragma unroll
        for (int k = 0; k < 4; ++k) acc2[k] += d2[k];
        dec8p(b, d2);
#pragma unroll
        for (int k = 0; k < 4; ++k) acc2[k + 4] += d2[k];
    }
    for (; e <= end; ++e) {               // includes self term at e==end
        int s = (e < end) ? csrc[e] : n;
        uint4 v = g16[(size_t)s * 8 + lane];
        uint2 a, b;
        a.x = v.x; a.y = v.y; b.x = v.z; b.y = v.w;
        dec8p(a, d2);
#pragma unroll
        for (int k = 0; k < 4; ++k) acc2[k] += d2[k];
        dec8p(b, d2);
#pragma unroll
        for (int k = 0; k < 4; ++k) acc2[k + 4] += d2[k];
    }
    float dn = dinv[n];
    const float4* bv = (const float4*)(bias + lane * 16);
    float bb[16];
    float4 b0 = bv[0], b1 = bv[1], b2 = bv[2], b3 = bv[3];
    bb[0]=b0.x; bb[1]=b0.y; bb[2]=b0.z; bb[3]=b0.w;
    bb[4]=b1.x; bb[5]=b1.y; bb[6]=b1.z; bb[7]=b1.w;
    bb[8]=b2.x; bb[9]=b2.y; bb[10]=b2.z; bb[11]=b2.w;
    bb[12]=b3.x; bb[13]=b3.y; bb[14]=b3.z; bb[15]=b3.w;
    float o[16];
#pragma unroll
    for (int j = 0; j < 16; ++j)
        o[j] = fmaxf(fmaf(acc2[j >> 1][j & 1], dn, bb[j]), 0.f);
    uint4 w;
    w.x = enc_pk4(o[0], o[1], o[2], o[3]);
    w.y = enc_pk4(o[4], o[5], o[6], o[7]);
    w.z = enc_pk4(o[8], o[9], o[10], o[11]);
    w.w = enc_pk4(o[12], o[13], o[14], o[15]);
    ((uint4*)hOut)[(size_t)n * 8 + lane] = w;
}

// -------- pooling stage 1: 16 segments/graph, partials to psum_seg (no atomics) --------
__global__ __launch_bounds__(256) void poolseg_kernel(const unsigned char* __restrict__ h8,
                                                      const int* __restrict__ batch,
                                                      float* __restrict__ psum_seg) {
    int g = blockIdx.x >> 4;
    int seg = blockIdx.x & (PSEG - 1);
    int t = threadIdx.x;
    int lo = 0, hi = NN;
    while (lo < hi) { int m = (lo + hi) >> 1; if (batch[m] < g) lo = m + 1; else hi = m; }
    int lb = lo;
    lo = 0; hi = NN;
    while (lo < hi) { int m = (lo + hi) >> 1; if (batch[m] <= g) lo = m + 1; else hi = m; }
    int ub = lo;
    int len = ub - lb;
    int b0 = lb + (int)(((long long)len * seg) / PSEG);
    int b1 = lb + (int)(((long long)len * (seg + 1)) / PSEG);

    int fg = t & 15;        // feature group
    int rg = t >> 4;        // row slot 0..15
    const uint2* gp = (const uint2*)h8;
    f32x2 acc2[4] = {};
    f32x2 d2[4];
    for (int n = b0 + rg; n < b1; n += 16) {
        uint2 v = gp[(size_t)n * 16 + fg];
        dec8p(v, d2);
#pragma unroll
        for (int k = 0; k < 4; ++k) acc2[k] += d2[k];
    }
    __shared__ float red[256][8];
#pragma unroll
    for (int j = 0; j < 8; ++j) red[t][j] = acc2[j >> 1][j & 1];
    __syncthreads();
    for (int off = 8; off >= 1; off >>= 1) {
        if (rg < off) {
#pragma unroll
            for (int j = 0; j < 8; ++j) red[t][j] += red[t + off * 16][j];
        }
        __syncthreads();
    }
    if (t < 16) {
#pragma unroll
        for (int j = 0; j < 8; ++j)
            psum_seg[((size_t)g * PSEG + seg) * HH + t * 8 + j] = red[t][j];
    }
}

// -------- pooling stage 2 + MLP + log_softmax: one block per graph --------
__global__ __launch_bounds__(128) void mlp2_kernel(const float* __restrict__ psum_seg,
                                                   const int* __restrict__ batch,
                                                   const float* __restrict__ Wl1,
                                                   const float* __restrict__ bl1,
                                                   const float* __restrict__ Wl2,
                                                   const float* __restrict__ bl2,
                                                   float* __restrict__ out) {
    __shared__ float p[128], o1[128], lg[CC];
    int g = blockIdx.x, t = threadIdx.x;
    int lo = 0, hi = NN;
    while (lo < hi) { int m = (lo + hi) >> 1; if (batch[m] < g) lo = m + 1; else hi = m; }
    int lb = lo;
    lo = 0; hi = NN;
    while (lo < hi) { int m = (lo + hi) >> 1; if (batch[m] <= g) lo = m + 1; else hi = m; }
    int len = lo - lb;
    float a = 0.f;
#pragma unroll
    for (int s = 0; s < PSEG; ++s)
        a += psum_seg[((size_t)g * PSEG + s) * HH + t];
    p[t] = a / fmaxf((float)len, 1.f);
    __syncthreads();
    float acc = bl1[t];
    for (int k = 0; k < HH; ++k) acc = fmaf(p[k], Wl1[k * HH + t], acc);
    o1[t] = fmaxf(acc, 0.f);
    __syncthreads();
    if (t < CC) {
        float a2 = bl2[t];
        for (int j = 0; j < HH; ++j) a2 = fmaf(o1[j], Wl2[j * CC + t], a2);
        lg[t] = a2;
    }
    __syncthreads();
    if (t == 0) {
        float m = lg[0];
        for (int c = 1; c < CC; ++c) m = fmaxf(m, lg[c]);
        float s = 0.f;
        for (int c = 0; c < CC; ++c) s += expf(lg[c] - m);
        float ls = logf(s);
        for (int c = 0; c < CC; ++c) out[g * CC + c] = lg[c] - m - ls;
    }
}

extern "C" void kernel_launch(void* const* d_in, const int* in_sizes, int n_in,
                              void* d_out, int out_size, void* d_ws, size_t ws_size,
                              hipStream_t stream) {
    const float* x   = (const float*)d_in[0];
    const int*   ei  = (const int*)d_in[1];
    const int*   bat = (const int*)d_in[2];
    const float* W1  = (const float*)d_in[3];
    const float* b1  = (const float*)d_in[4];
    const float* Wr1 = (const float*)d_in[5];
    const float* br1 = (const float*)d_in[6];
    const float* W2  = (const float*)d_in[7];
    const float* b2  = (const float*)d_in[8];
    const float* Wr  = (const float*)d_in[9];
    const float* br  = (const float*)d_in[10];
    const float* Wl1 = (const float*)d_in[11];
    const float* bl1 = (const float*)d_in[12];
    const float* Wl2 = (const float*)d_in[13];
    const float* bl2 = (const float*)d_in[14];
    float* out = (float*)d_out;

    // workspace carve-up (256B aligned)
    char* base = (char*)d_ws;
    size_t off = 0;
    auto alloc = [&](size_t bytes) {
        void* p = base + off;
        off += (bytes + 255) & ~(size_t)255;
        return p;
    };
    unsigned char* x8   = (unsigned char*)alloc((size_t)NN * HH);
    unsigned char* h8   = (unsigned char*)alloc((size_t)NN * HH);
    unsigned char* t8   = (unsigned char*)alloc((size_t)NN * HH);
    unsigned* eb32 = (unsigned*)alloc((size_t)NE * 4);          // compact, 6.4 MB
    int*   cc     = (int*)alloc((size_t)NCHUNK * NBUCKET * 4);  // 1 MB
    int*   csrc   = (int*)alloc((size_t)NE * 4);
    int*   offs   = (int*)alloc((size_t)(NN + 1) * 4);
    float* dinv   = (float*)alloc((size_t)NN * 4);
    int*   tot    = (int*)alloc(NBUCKET * 4);
    unsigned short* Wpack = (unsigned short*)alloc(3 * 16384 * 2);
    float* bc     = (float*)alloc(3 * HH * 4);
    float* psum_seg = (float*)alloc((size_t)GG * PSEG * HH * 4);
    (void)ws_size; (void)in_sizes; (void)n_in; (void)out_size;

    // fused input-convert + weight combine
    combo_kernel<<<XCONV_BLOCKS + 192, 256, 0, stream>>>(x, x8, W1, b1, Wr1, br1,
                                                         W2, b2, Wr, br, Wpack, bc);

    // deterministic partition: 4 kernels, no global atomics
    partA1_kernel<<<NCHUNK, 256, 0, stream>>>(ei, cc);
    partA2_kernel<<<NBUCKET, 256, 0, stream>>>(cc, tot);
    partA3_kernel<<<NCHUNK, 256, 0, stream>>>(ei, cc, tot, eb32);
    partB_kernel<<<NBUCKET, 256, 0, stream>>>(eb32, tot, offs, dinv, csrc);

    const int GEMM_BLOCKS = (NN + 63) / 64;
    const int AGG_BLOCKS = (NN + 31) / 32;
    // layer 0
    gemm_mfma_kernel<<<GEMM_BLOCKS, 256, 0, stream>>>(x8, Wpack, dinv, t8, NN);
    agg_relu_kernel<<<AGG_BLOCKS, 256, 0, stream>>>(t8, offs, csrc, dinv, bc, h8);
    // layer 1
    gemm_mfma_kernel<<<GEMM_BLOCKS, 256, 0, stream>>>(h8, Wpack + 16384, dinv, t8, NN);
    agg_relu_kernel<<<AGG_BLOCKS, 256, 0, stream>>>(t8, offs, csrc, dinv, bc + HH, h8);
    // layer 2
    gemm_mfma_kernel<<<GEMM_BLOCKS, 256, 0, stream>>>(h8, Wpack + 2 * 16384, dinv, t8, NN);
    agg_relu_kernel<<<AGG_BLOCKS, 256, 0, stream>>>(t8, offs, csrc, dinv, bc + 2 * HH, h8);

    // pooling (parallel segments, no atomics) + readout
    poolseg_kernel<<<GG * PSEG, 256, 0, stream>>>(h8, bat, psum_seg);
    mlp2_kernel<<<GG, 128, 0, stream>>>(psum_seg, bat, Wl1, bl1, Wl2, bl2, out);
}

// Round 16
// 242.670 us; speedup vs baseline: 1.1650x; 1.0205x over previous
//
#include <hip/hip_runtime.h>
#include <hip/hip_bf16.h>
#include <hip/hip_fp8.h>

#define NN 100000
#define NE 1600000
#define FF 128
#define HH 128
#define CC 10
#define GG 64

#define NCHUNK 2048
#define CE 782            // ceil(NE/NCHUNK)
#define NBUCKET 128
#define BSPAN 782         // ceil(NN/NBUCKET)
#define PSEG 16
#define SRCBITS 17        // NN < 131072

typedef __attribute__((ext_vector_type(8))) short short8;
typedef __attribute__((ext_vector_type(4))) float f32x4;
typedef __attribute__((ext_vector_type(2))) float f32x2;

__device__ inline unsigned short f2bf(float f) {
    union { float f; unsigned int i; } x;
    x.f = f;
    unsigned int r = x.i + 0x7FFF + ((x.i >> 16) & 1);  // RNE
    return (unsigned short)(r >> 16);
}
__device__ inline unsigned char f8enc_sw(float v) {
    __hip_fp8_e4m3 q(v);
    return (unsigned char)q.__x;
}
__device__ inline float f8dec(unsigned char b) {
    __hip_fp8_e4m3 q;
    q.__x = (__hip_fp8_storage_t)b;
    return (float)q;
}

#if defined(__has_builtin)
#if __has_builtin(__builtin_amdgcn_cvt_pk_f32_fp8)
#define HAVE_CVT_PK_F32_FP8 1
#endif
#if __has_builtin(__builtin_amdgcn_cvt_pk_fp8_f32)
#define HAVE_CVT_PK_FP8 1
#endif
#endif

// decode 8 fp8 (uint2) -> 8 f32 (scalar out)
__device__ inline void dec8(uint2 v, float* o) {
#ifdef HAVE_CVT_PK_F32_FP8
    f32x2 p;
    p = __builtin_amdgcn_cvt_pk_f32_fp8(v.x, false); o[0] = p[0]; o[1] = p[1];
    p = __builtin_amdgcn_cvt_pk_f32_fp8(v.x, true);  o[2] = p[0]; o[3] = p[1];
    p = __builtin_amdgcn_cvt_pk_f32_fp8(v.y, false); o[4] = p[0]; o[5] = p[1];
    p = __builtin_amdgcn_cvt_pk_f32_fp8(v.y, true);  o[6] = p[0]; o[7] = p[1];
#else
#pragma unroll
    for (int j = 0; j < 4; ++j) {
        o[j]     = f8dec((v.x >> (8 * j)) & 0xFF);
        o[j + 4] = f8dec((v.y >> (8 * j)) & 0xFF);
    }
#endif
}
// decode 8 fp8 -> 4 packed f32x2 (enables v_pk_add_f32 accumulate)
__device__ inline void dec8p(uint2 v, f32x2* o) {
#ifdef HAVE_CVT_PK_F32_FP8
    o[0] = __builtin_amdgcn_cvt_pk_f32_fp8(v.x, false);
    o[1] = __builtin_amdgcn_cvt_pk_f32_fp8(v.x, true);
    o[2] = __builtin_amdgcn_cvt_pk_f32_fp8(v.y, false);
    o[3] = __builtin_amdgcn_cvt_pk_f32_fp8(v.y, true);
#else
    float d[8]; dec8(v, d);
#pragma unroll
    for (int j = 0; j < 4; ++j) { o[j][0] = d[2 * j]; o[j][1] = d[2 * j + 1]; }
#endif
}
// encode 4 f32 -> packed fp8 dword (HW v_cvt_pk_fp8_f32 when available)
__device__ inline unsigned enc_pk4(float a, float b, float c, float d) {
#ifdef HAVE_CVT_PK_FP8
    int w = __builtin_amdgcn_cvt_pk_fp8_f32(a, b, 0, false);
    w = __builtin_amdgcn_cvt_pk_fp8_f32(c, d, w, true);
    return (unsigned)w;
#else
    return (unsigned)f8enc_sw(a) | ((unsigned)f8enc_sw(b) << 8) |
           ((unsigned)f8enc_sw(c) << 16) | ((unsigned)f8enc_sw(d) << 24);
#endif
}
__device__ inline unsigned char f8enc1(float v) {
#ifdef HAVE_CVT_PK_FP8
    return (unsigned char)(__builtin_amdgcn_cvt_pk_fp8_f32(v, v, 0, false) & 0xFF);
#else
    return f8enc_sw(v);
#endif
}

// -------- weight combine + pack into MFMA B-fragment order (weights only) --------
__global__ __launch_bounds__(256) void combw_kernel(const float* __restrict__ W1, const float* __restrict__ b1,
                                                    const float* __restrict__ Wr1, const float* __restrict__ br1,
                                                    const float* __restrict__ W2, const float* __restrict__ b2,
                                                    const float* __restrict__ Wr, const float* __restrict__ br,
                                                    unsigned short* __restrict__ Wpack, float* __restrict__ bc) {
    int idx = blockIdx.x * 256 + threadIdx.x;   // < 3*16384
    if (idx >= 3 * 16384) return;
    int l = idx / 16384, rem = idx % 16384;
    int cb = rem / 2048;
    int kb = (rem / 512) % 4;
    int lane = (rem / 8) % 64;
    int j = rem % 8;
    int k = kb * 32 + (lane >> 4) * 8 + j;
    int c = cb * 16 + (lane & 15);
    int wi = k * HH + c;
    float v = (l == 0) ? 0.95f * W1[wi] + 0.05f * Wr1[wi]
                       : 0.95f * W2[(l - 1) * 16384 + wi] + 0.05f * Wr[wi];
    Wpack[idx] = f2bf(v);
    if (rem < HH) {
        bc[l * HH + rem] = (l == 0) ? 0.95f * b1[rem] + 0.05f * br1[rem]
                                    : 0.95f * b2[(l - 1) * HH + rem] + 0.05f * br[rem];
    }
}

// ---- A1: per-chunk per-bucket counts (LDS histogram, no global atomics) ----
__global__ __launch_bounds__(256) void partA1_kernel(const int* __restrict__ ei,
                                                     int* __restrict__ cc) {
    __shared__ int h[NBUCKET];
    int c = blockIdx.x, t = threadIdx.x;
    if (t < NBUCKET) h[t] = 0;
    __syncthreads();
    int beg = c * CE, end = min(beg + CE, NE);
    for (int e = beg + t; e < end; e += 256)
        atomicAdd(&h[ei[NE + e] / BSPAN], 1);
    __syncthreads();
    if (t < NBUCKET) cc[c * NBUCKET + t] = h[t];
}

// ---- A2: per-bucket exclusive scan over 2048 chunks (in-place on cc); tot[b] out ----
__global__ __launch_bounds__(256) void partA2_kernel(int* __restrict__ cc,
                                                     int* __restrict__ tot) {
    __shared__ int sh[256];
    int b = blockIdx.x, t = threadIdx.x;
    int v[8]; int s = 0;
#pragma unroll
    for (int i = 0; i < 8; ++i) { v[i] = cc[(t * 8 + i) * NBUCKET + b]; s += v[i]; }
    sh[t] = s; __syncthreads();
    for (int off = 1; off < 256; off <<= 1) {
        int x = (t >= off) ? sh[t - off] : 0; __syncthreads();
        sh[t] += x; __syncthreads();
    }
    int excl = sh[t] - s;
#pragma unroll
    for (int i = 0; i < 8; ++i) {
        cc[(t * 8 + i) * NBUCKET + b] = excl;
        excl += v[i];
    }
    if (t == 255) tot[b] = sh[255];
}

// ---- A3: scatter packed (local_dst<<17 | src) into COMPACT bucketed eb32 ----
__global__ __launch_bounds__(256) void partA3_kernel(const int* __restrict__ ei,
                                                     const int* __restrict__ cc,
                                                     const int* __restrict__ tot,
                                                     unsigned* __restrict__ eb32) {
    __shared__ int stot[NBUCKET];
    __shared__ int cur[NBUCKET];
    int c = blockIdx.x, t = threadIdx.x;
    if (t < NBUCKET) stot[t] = tot[t];
    __syncthreads();
    for (int off = 1; off < NBUCKET; off <<= 1) {
        int x = (t < NBUCKET && t >= off) ? stot[t - off] : 0;
        __syncthreads();
        if (t < NBUCKET) stot[t] += x;
        __syncthreads();
    }
    if (t < NBUCKET) cur[t] = (stot[t] - tot[t]) + cc[c * NBUCKET + t];
    __syncthreads();
    int beg = c * CE, end = min(beg + CE, NE);
    for (int e = beg + t; e < end; e += 256) {
        int d = ei[NE + e];
        int s = ei[e];
        int b = d / BSPAN;
        int ld = d - b * BSPAN;
        int p = atomicAdd(&cur[b], 1);
        eb32[p] = (unsigned)s | ((unsigned)ld << SRCBITS);
    }
}

// ---- B (fused): bucket hist -> offs + dinv -> CSR scatter (eb slice L2-hot) ----
__global__ __launch_bounds__(256) void partB_kernel(const unsigned* __restrict__ eb32,
                                                    const int* __restrict__ tot,
                                                    int* __restrict__ offs,
                                                    float* __restrict__ dinv,
                                                    int* __restrict__ csrc) {
    __shared__ int hcnt[BSPAN];
    __shared__ int lcur[BSPAN];
    __shared__ int sh[256];
    __shared__ int gbase_sh;
    int b = blockIdx.x, t = threadIdx.x;
    int lo = b * BSPAN;
    int span = min(BSPAN, NN - lo);
    if (span <= 0) return;
    for (int i = t; i < span; i += 256) hcnt[i] = 0;
    if (t == 0) {
        int g = 0;
        for (int i = 0; i < b; ++i) g += tot[i];
        gbase_sh = g;
    }
    __syncthreads();
    int gbase = gbase_sh;
    int len = tot[b];
    const unsigned* ebb = eb32 + (size_t)gbase;
    for (int e = t; e < len; e += 256)
        atomicAdd(&hcnt[ebb[e] >> SRCBITS], 1);
    __syncthreads();
    int base = t * 4;
    int v[4]; int s = 0;
#pragma unroll
    for (int j = 0; j < 4; ++j) { int i = base + j; v[j] = (i < span) ? hcnt[i] : 0; s += v[j]; }
    sh[t] = s; __syncthreads();
    for (int off = 1; off < 256; off <<= 1) {
        int x = (t >= off) ? sh[t - off] : 0; __syncthreads();
        sh[t] += x; __syncthreads();
    }
    int excl = sh[t] - s + gbase;
#pragma unroll
    for (int j = 0; j < 4; ++j) {
        int i = base + j;
        if (i < span) {
            offs[lo + i] = excl;
            lcur[i] = excl;
            dinv[lo + i] = rsqrtf((float)v[j] + 1.0f);
            excl += v[j];
        }
    }
    if (b == NBUCKET - 1 && t == 0) offs[NN] = NE;
    __syncthreads();
    for (int e = t; e < len; e += 256) {
        unsigned pr = ebb[e];
        int p = atomicAdd(&lcur[pr >> SRCBITS], 1);
        csrc[p] = (int)(pr & ((1u << SRCBITS) - 1));
    }
}

// ------- MFMA GEMM layer 0: reads f32 x directly (bf16 fragments in-register) -------
__global__ __launch_bounds__(256) void gemm_f32_kernel(const float* __restrict__ A,
                                                       const unsigned short* __restrict__ Wp,
                                                       const float* __restrict__ dinv,
                                                       unsigned char* __restrict__ out8,
                                                       int nrows) {
    __shared__ unsigned char f8s[64][128];
    int w = threadIdx.x >> 6;
    int l = threadIdx.x & 63;
    int m0 = blockIdx.x * 64 + w * 16;
    int kg = l >> 4;
    int cl = l & 15;
    int arow = m0 + cl;

    short8 a[4];
    if (arow < nrows) {
        const float4* Ar4 = (const float4*)(A + (size_t)arow * HH);
#pragma unroll
        for (int kb = 0; kb < 4; ++kb) {
            float4 u0 = Ar4[kb * 8 + kg * 2];
            float4 u1 = Ar4[kb * 8 + kg * 2 + 1];
            short8 tt;
            tt[0] = (short)f2bf(u0.x); tt[1] = (short)f2bf(u0.y);
            tt[2] = (short)f2bf(u0.z); tt[3] = (short)f2bf(u0.w);
            tt[4] = (short)f2bf(u1.x); tt[5] = (short)f2bf(u1.y);
            tt[6] = (short)f2bf(u1.z); tt[7] = (short)f2bf(u1.w);
            a[kb] = tt;
        }
    } else {
        short8 z = {};
#pragma unroll
        for (int kb = 0; kb < 4; ++kb) a[kb] = z;
    }

    float dv[4];
#pragma unroll
    for (int r = 0; r < 4; ++r) {
        int orow = m0 + kg * 4 + r;
        dv[r] = (orow < nrows) ? dinv[orow] : 0.f;
    }

#pragma unroll
    for (int cb = 0; cb < 8; ++cb) {
        f32x4 acc = {0.f, 0.f, 0.f, 0.f};
#pragma unroll
        for (int kb = 0; kb < 4; ++kb) {
            short8 b = *(const short8*)(Wp + (size_t)(cb * 4 + kb) * 512 + l * 8);
            acc = __builtin_amdgcn_mfma_f32_16x16x32_bf16(a[kb], b, acc, 0, 0, 0);
        }
#pragma unroll
        for (int r = 0; r < 4; ++r)
            f8s[w * 16 + kg * 4 + r][cb * 16 + cl] = f8enc1(acc[r] * dv[r]);
    }
    __syncthreads();
    int blk0 = blockIdx.x * 64;
    for (int u = threadIdx.x; u < 512; u += 256) {
        int row = u >> 3, c16 = u & 7;
        int grow = blk0 + row;
        if (grow < nrows)
            ((uint4*)out8)[(size_t)grow * 8 + c16] = ((const uint4*)&f8s[row][0])[c16];
    }
}

// ------- MFMA GEMM (fp8 input): t8 = rowscale(dinv) * (A8 @ Wc) -------
__global__ __launch_bounds__(256) void gemm_mfma_kernel(const unsigned char* __restrict__ A8,
                                                        const unsigned short* __restrict__ Wp,
                                                        const float* __restrict__ dinv,
                                                        unsigned char* __restrict__ out8,
                                                        int nrows) {
    __shared__ unsigned char f8s[64][128];
    int w = threadIdx.x >> 6;
    int l = threadIdx.x & 63;
    int m0 = blockIdx.x * 64 + w * 16;
    int kg = l >> 4;
    int cl = l & 15;
    int arow = m0 + cl;

    short8 a[4];
    if (arow < nrows) {
        const uint2* Ar = (const uint2*)(A8 + (size_t)arow * HH);
#pragma unroll
        for (int kb = 0; kb < 4; ++kb) {
            uint2 v = Ar[kb * 4 + kg];
            float d[8]; dec8(v, d);
            short8 t;
#pragma unroll
            for (int j = 0; j < 8; ++j) t[j] = (short)f2bf(d[j]);
            a[kb] = t;
        }
    } else {
        short8 z = {};
#pragma unroll
        for (int kb = 0; kb < 4; ++kb) a[kb] = z;
    }

    float dv[4];
#pragma unroll
    for (int r = 0; r < 4; ++r) {
        int orow = m0 + kg * 4 + r;
        dv[r] = (orow < nrows) ? dinv[orow] : 0.f;
    }

#pragma unroll
    for (int cb = 0; cb < 8; ++cb) {
        f32x4 acc = {0.f, 0.f, 0.f, 0.f};
#pragma unroll
        for (int kb = 0; kb < 4; ++kb) {
            short8 b = *(const short8*)(Wp + (size_t)(cb * 4 + kb) * 512 + l * 8);
            acc = __builtin_amdgcn_mfma_f32_16x16x32_bf16(a[kb], b, acc, 0, 0, 0);
        }
#pragma unroll
        for (int r = 0; r < 4; ++r)
            f8s[w * 16 + kg * 4 + r][cb * 16 + cl] = f8enc1(acc[r] * dv[r]);
    }
    __syncthreads();
    int blk0 = blockIdx.x * 64;
    for (int u = threadIdx.x; u < 512; u += 256) {
        int row = u >> 3, c16 = u & 7;
        int grow = blk0 + row;
        if (grow < nrows)
            ((uint4*)out8)[(size_t)grow * 8 + c16] = ((const uint4*)&f8s[row][0])[c16];
    }
}

// ---- aggregation: 8 lanes/node, uint4 rows, 8-deep unroll for MLP ----
__global__ __launch_bounds__(256) void agg_relu_kernel(const unsigned char* __restrict__ t8,
                                                       const int* __restrict__ offs,
                                                       const int* __restrict__ csrc,
                                                       const float* __restrict__ dinv,
                                                       const float* __restrict__ bias,
                                                       unsigned char* __restrict__ hOut) {
    int n = blockIdx.x * 32 + (threadIdx.x >> 3);
    if (n >= NN) return;
    int lane = threadIdx.x & 7;           // features lane*16 .. lane*16+15
    int beg = offs[n], end = offs[n + 1];
    const uint4* g16 = (const uint4*)t8;  // row = 8 uint4 (128 fp8)
    f32x2 acc2[8] = {};
    f32x2 d2[4];
    int e = beg;
    for (; e + 7 < end; e += 8) {
        uint4 v[8];
#pragma unroll
        for (int q = 0; q < 8; ++q)
            v[q] = g16[(size_t)csrc[e + q] * 8 + lane];
#pragma unroll
        for (int q = 0; q < 8; ++q) {
            uint2 a, b;
            a.x = v[q].x; a.y = v[q].y; b.x = v[q].z; b.y = v[q].w;
            dec8p(a, d2);
#pragma unroll
            for (int k = 0; k < 4; ++k) acc2[k] += d2[k];
            dec8p(b, d2);
#pragma unroll
            for (int k = 0; k < 4; ++k) acc2[k + 4] += d2[k];
        }
    }
    for (; e <= end; ++e) {               // includes self term at e==end
        int s = (e < end) ? csrc[e] : n;
        uint4 v = g16[(size_t)s * 8 + lane];
        uint2 a, b;
        a.x = v.x; a.y = v.y; b.x = v.z; b.y = v.w;
        dec8p(a, d2);
#pragma unroll
        for (int k = 0; k < 4; ++k) acc2[k] += d2[k];
        dec8p(b, d2);
#pragma unroll
        for (int k = 0; k < 4; ++k) acc2[k + 4] += d2[k];
    }
    float dn = dinv[n];
    const float4* bv = (const float4*)(bias + lane * 16);
    float bb[16];
    float4 b0 = bv[0], b1 = bv[1], b2 = bv[2], b3 = bv[3];
    bb[0]=b0.x; bb[1]=b0.y; bb[2]=b0.z; bb[3]=b0.w;
    bb[4]=b1.x; bb[5]=b1.y; bb[6]=b1.z; bb[7]=b1.w;
    bb[8]=b2.x; bb[9]=b2.y; bb[10]=b2.z; bb[11]=b2.w;
    bb[12]=b3.x; bb[13]=b3.y; bb[14]=b3.z; bb[15]=b3.w;
    float o[16];
#pragma unroll
    for (int j = 0; j < 16; ++j)
        o[j] = fmaxf(fmaf(acc2[j >> 1][j & 1], dn, bb[j]), 0.f);
    uint4 w;
    w.x = enc_pk4(o[0], o[1], o[2], o[3]);
    w.y = enc_pk4(o[4], o[5], o[6], o[7]);
    w.z = enc_pk4(o[8], o[9], o[10], o[11]);
    w.w = enc_pk4(o[12], o[13], o[14], o[15]);
    ((uint4*)hOut)[(size_t)n * 8 + lane] = w;
}

// -------- pooling stage 1: 16 segments/graph, partials to psum_seg (no atomics) --------
__global__ __launch_bounds__(256) void poolseg_kernel(const unsigned char* __restrict__ h8,
                                                      const int* __restrict__ batch,
                                                      float* __restrict__ psum_seg) {
    int g = blockIdx.x >> 4;
    int seg = blockIdx.x & (PSEG - 1);
    int t = threadIdx.x;
    int lo = 0, hi = NN;
    while (lo < hi) { int m = (lo + hi) >> 1; if (batch[m] < g) lo = m + 1; else hi = m; }
    int lb = lo;
    lo = 0; hi = NN;
    while (lo < hi) { int m = (lo + hi) >> 1; if (batch[m] <= g) lo = m + 1; else hi = m; }
    int ub = lo;
    int len = ub - lb;
    int b0 = lb + (int)(((long long)len * seg) / PSEG);
    int b1 = lb + (int)(((long long)len * (seg + 1)) / PSEG);

    int fg = t & 15;        // feature group
    int rg = t >> 4;        // row slot 0..15
    const uint2* gp = (const uint2*)h8;
    f32x2 acc2[4] = {};
    f32x2 d2[4];
    for (int n = b0 + rg; n < b1; n += 16) {
        uint2 v = gp[(size_t)n * 16 + fg];
        dec8p(v, d2);
#pragma unroll
        for (int k = 0; k < 4; ++k) acc2[k] += d2[k];
    }
    __shared__ float red[256][8];
#pragma unroll
    for (int j = 0; j < 8; ++j) red[t][j] = acc2[j >> 1][j & 1];
    __syncthreads();
    for (int off = 8; off >= 1; off >>= 1) {
        if (rg < off) {
#pragma unroll
            for (int j = 0; j < 8; ++j) red[t][j] += red[t + off * 16][j];
        }
        __syncthreads();
    }
    if (t < 16) {
#pragma unroll
        for (int j = 0; j < 8; ++j)
            psum_seg[((size_t)g * PSEG + seg) * HH + t * 8 + j] = red[t][j];
    }
}

// -------- pooling stage 2 + MLP + log_softmax: one block per graph --------
__global__ __launch_bounds__(128) void mlp2_kernel(const float* __restrict__ psum_seg,
                                                   const int* __restrict__ batch,
                                                   const float* __restrict__ Wl1,
                                                   const float* __restrict__ bl1,
                                                   const float* __restrict__ Wl2,
                                                   const float* __restrict__ bl2,
                                                   float* __restrict__ out) {
    __shared__ float p[128], o1[128], lg[CC];
    int g = blockIdx.x, t = threadIdx.x;
    int lo = 0, hi = NN;
    while (lo < hi) { int m = (lo + hi) >> 1; if (batch[m] < g) lo = m + 1; else hi = m; }
    int lb = lo;
    lo = 0; hi = NN;
    while (lo < hi) { int m = (lo + hi) >> 1; if (batch[m] <= g) lo = m + 1; else hi = m; }
    int len = lo - lb;
    float a = 0.f;
#pragma unroll
    for (int s = 0; s < PSEG; ++s)
        a += psum_seg[((size_t)g * PSEG + s) * HH + t];
    p[t] = a / fmaxf((float)len, 1.f);
    __syncthreads();
    float acc = bl1[t];
    for (int k = 0; k < HH; ++k) acc = fmaf(p[k], Wl1[k * HH + t], acc);
    o1[t] = fmaxf(acc, 0.f);
    __syncthreads();
    if (t < CC) {
        float a2 = bl2[t];
        for (int j = 0; j < HH; ++j) a2 = fmaf(o1[j], Wl2[j * CC + t], a2);
        lg[t] = a2;
    }
    __syncthreads();
    if (t == 0) {
        float m = lg[0];
        for (int c = 1; c < CC; ++c) m = fmaxf(m, lg[c]);
        float s = 0.f;
        for (int c = 0; c < CC; ++c) s += expf(lg[c] - m);
        float ls = logf(s);
        for (int c = 0; c < CC; ++c) out[g * CC + c] = lg[c] - m - ls;
    }
}

extern "C" void kernel_launch(void* const* d_in, const int* in_sizes, int n_in,
                              void* d_out, int out_size, void* d_ws, size_t ws_size,
                              hipStream_t stream) {
    const float* x   = (const float*)d_in[0];
    const int*   ei  = (const int*)d_in[1];
    const int*   bat = (const int*)d_in[2];
    const float* W1  = (const float*)d_in[3];
    const float* b1  = (const float*)d_in[4];
    const float* Wr1 = (const float*)d_in[5];
    const float* br1 = (const float*)d_in[6];
    const float* W2  = (const float*)d_in[7];
    const float* b2  = (const float*)d_in[8];
    const float* Wr  = (const float*)d_in[9];
    const float* br  = (const float*)d_in[10];
    const float* Wl1 = (const float*)d_in[11];
    const float* bl1 = (const float*)d_in[12];
    const float* Wl2 = (const float*)d_in[13];
    const float* bl2 = (const float*)d_in[14];
    float* out = (float*)d_out;

    // workspace carve-up (256B aligned)
    char* base = (char*)d_ws;
    size_t off = 0;
    auto alloc = [&](size_t bytes) {
        void* p = base + off;
        off += (bytes + 255) & ~(size_t)255;
        return p;
    };
    unsigned char* h8   = (unsigned char*)alloc((size_t)NN * HH);
    unsigned char* t8   = (unsigned char*)alloc((size_t)NN * HH);
    unsigned* eb32 = (unsigned*)alloc((size_t)NE * 4);          // compact, 6.4 MB
    int*   cc     = (int*)alloc((size_t)NCHUNK * NBUCKET * 4);  // 1 MB
    int*   csrc   = (int*)alloc((size_t)NE * 4);
    int*   offs   = (int*)alloc((size_t)(NN + 1) * 4);
    float* dinv   = (float*)alloc((size_t)NN * 4);
    int*   tot    = (int*)alloc(NBUCKET * 4);
    unsigned short* Wpack = (unsigned short*)alloc(3 * 16384 * 2);
    float* bc     = (float*)alloc(3 * HH * 4);
    float* psum_seg = (float*)alloc((size_t)GG * PSEG * HH * 4);
    (void)ws_size; (void)in_sizes; (void)n_in; (void)out_size;

    // weight combine (weights only; x is consumed directly by layer-0 GEMM)
    combw_kernel<<<192, 256, 0, stream>>>(W1, b1, Wr1, br1, W2, b2, Wr, br, Wpack, bc);

    // deterministic partition: 4 kernels, no global atomics
    partA1_kernel<<<NCHUNK, 256, 0, stream>>>(ei, cc);
    partA2_kernel<<<NBUCKET, 256, 0, stream>>>(cc, tot);
    partA3_kernel<<<NCHUNK, 256, 0, stream>>>(ei, cc, tot, eb32);
    partB_kernel<<<NBUCKET, 256, 0, stream>>>(eb32, tot, offs, dinv, csrc);

    const int GEMM_BLOCKS = (NN + 63) / 64;
    const int AGG_BLOCKS = (NN + 31) / 32;
    // layer 0 (reads f32 x directly)
    gemm_f32_kernel<<<GEMM_BLOCKS, 256, 0, stream>>>(x, Wpack, dinv, t8, NN);
    agg_relu_kernel<<<AGG_BLOCKS, 256, 0, stream>>>(t8, offs, csrc, dinv, bc, h8);
    // layer 1
    gemm_mfma_kernel<<<GEMM_BLOCKS, 256, 0, stream>>>(h8, Wpack + 16384, dinv, t8, NN);
    agg_relu_kernel<<<AGG_BLOCKS, 256, 0, stream>>>(t8, offs, csrc, dinv, bc + HH, h8);
    // layer 2
    gemm_mfma_kernel<<<GEMM_BLOCKS, 256, 0, stream>>>(h8, Wpack + 2 * 16384, dinv, t8, NN);
    agg_relu_kernel<<<AGG_BLOCKS, 256, 0, stream>>>(t8, offs, csrc, dinv, bc + 2 * HH, h8);

    // pooling (parallel segments, no atomics) + readout
    poolseg_kernel<<<GG * PSEG, 256, 0, stream>>>(h8, bat, psum_seg);
    mlp2_kernel<<<GG, 128, 0, stream>>>(psum_seg, bat, Wl1, bl1, Wl2, bl2, out);
}

// Round 17
// 226.229 us; speedup vs baseline: 1.2497x; 1.0727x over previous
//
#include <hip/hip_runtime.h>
#include <hip/hip_bf16.h>
#include <hip/hip_fp8.h>

#define NN 100000
#define NE 1600000
#define FF 128
#define HH 128
#define CC 10
#define GG 64

#define NCHUNK 2048
#define CE 782            // ceil(NE/NCHUNK)
#define NBUCKET 128
#define BSPAN 782         // ceil(NN/NBUCKET)
#define PSEG 16
#define SRCBITS 17        // NN < 131072

typedef __attribute__((ext_vector_type(8))) short short8;
typedef __attribute__((ext_vector_type(4))) float f32x4;
typedef __attribute__((ext_vector_type(2))) float f32x2;

__device__ inline unsigned short f2bf(float f) {
    union { float f; unsigned int i; } x;
    x.f = f;
    unsigned int r = x.i + 0x7FFF + ((x.i >> 16) & 1);  // RNE
    return (unsigned short)(r >> 16);
}
__device__ inline unsigned char f8enc_sw(float v) {
    __hip_fp8_e4m3 q(v);
    return (unsigned char)q.__x;
}
__device__ inline float f8dec(unsigned char b) {
    __hip_fp8_e4m3 q;
    q.__x = (__hip_fp8_storage_t)b;
    return (float)q;
}

#if defined(__has_builtin)
#if __has_builtin(__builtin_amdgcn_cvt_pk_f32_fp8)
#define HAVE_CVT_PK_F32_FP8 1
#endif
#if __has_builtin(__builtin_amdgcn_cvt_pk_fp8_f32)
#define HAVE_CVT_PK_FP8 1
#endif
#endif

// decode 8 fp8 (uint2) -> 8 f32 (scalar out)
__device__ inline void dec8(uint2 v, float* o) {
#ifdef HAVE_CVT_PK_F32_FP8
    f32x2 p;
    p = __builtin_amdgcn_cvt_pk_f32_fp8(v.x, false); o[0] = p[0]; o[1] = p[1];
    p = __builtin_amdgcn_cvt_pk_f32_fp8(v.x, true);  o[2] = p[0]; o[3] = p[1];
    p = __builtin_amdgcn_cvt_pk_f32_fp8(v.y, false); o[4] = p[0]; o[5] = p[1];
    p = __builtin_amdgcn_cvt_pk_f32_fp8(v.y, true);  o[6] = p[0]; o[7] = p[1];
#else
#pragma unroll
    for (int j = 0; j < 4; ++j) {
        o[j]     = f8dec((v.x >> (8 * j)) & 0xFF);
        o[j + 4] = f8dec((v.y >> (8 * j)) & 0xFF);
    }
#endif
}
// decode 8 fp8 -> 4 packed f32x2 (enables v_pk_add_f32 accumulate)
__device__ inline void dec8p(uint2 v, f32x2* o) {
#ifdef HAVE_CVT_PK_F32_FP8
    o[0] = __builtin_amdgcn_cvt_pk_f32_fp8(v.x, false);
    o[1] = __builtin_amdgcn_cvt_pk_f32_fp8(v.x, true);
    o[2] = __builtin_amdgcn_cvt_pk_f32_fp8(v.y, false);
    o[3] = __builtin_amdgcn_cvt_pk_f32_fp8(v.y, true);
#else
    float d[8]; dec8(v, d);
#pragma unroll
    for (int j = 0; j < 4; ++j) { o[j][0] = d[2 * j]; o[j][1] = d[2 * j + 1]; }
#endif
}
// encode 4 f32 -> packed fp8 dword (HW v_cvt_pk_fp8_f32 when available)
__device__ inline unsigned enc_pk4(float a, float b, float c, float d) {
#ifdef HAVE_CVT_PK_FP8
    int w = __builtin_amdgcn_cvt_pk_fp8_f32(a, b, 0, false);
    w = __builtin_amdgcn_cvt_pk_fp8_f32(c, d, w, true);
    return (unsigned)w;
#else
    return (unsigned)f8enc_sw(a) | ((unsigned)f8enc_sw(b) << 8) |
           ((unsigned)f8enc_sw(c) << 16) | ((unsigned)f8enc_sw(d) << 24);
#endif
}
__device__ inline unsigned char f8enc1(float v) {
#ifdef HAVE_CVT_PK_FP8
    return (unsigned char)(__builtin_amdgcn_cvt_pk_fp8_f32(v, v, 0, false) & 0xFF);
#else
    return f8enc_sw(v);
#endif
}
__device__ inline unsigned pack2bf(float a, float b) {
    return (unsigned)f2bf(a) | ((unsigned)f2bf(b) << 16);
}

// -------- weight combine + pack into MFMA B-fragment order (weights only) --------
__global__ __launch_bounds__(256) void combw_kernel(const float* __restrict__ W1, const float* __restrict__ b1,
                                                    const float* __restrict__ Wr1, const float* __restrict__ br1,
                                                    const float* __restrict__ W2, const float* __restrict__ b2,
                                                    const float* __restrict__ Wr, const float* __restrict__ br,
                                                    unsigned short* __restrict__ Wpack, float* __restrict__ bc) {
    int idx = blockIdx.x * 256 + threadIdx.x;   // < 3*16384
    if (idx >= 3 * 16384) return;
    int l = idx / 16384, rem = idx % 16384;
    int cb = rem / 2048;
    int kb = (rem / 512) % 4;
    int lane = (rem / 8) % 64;
    int j = rem % 8;
    int k = kb * 32 + (lane >> 4) * 8 + j;
    int c = cb * 16 + (lane & 15);
    int wi = k * HH + c;
    float v = (l == 0) ? 0.95f * W1[wi] + 0.05f * Wr1[wi]
                       : 0.95f * W2[(l - 1) * 16384 + wi] + 0.05f * Wr[wi];
    Wpack[idx] = f2bf(v);
    if (rem < HH) {
        bc[l * HH + rem] = (l == 0) ? 0.95f * b1[rem] + 0.05f * br1[rem]
                                    : 0.95f * b2[(l - 1) * HH + rem] + 0.05f * br[rem];
    }
}

// ---- A1: per-chunk per-bucket counts (LDS histogram, no global atomics) ----
__global__ __launch_bounds__(256) void partA1_kernel(const int* __restrict__ ei,
                                                     int* __restrict__ cc) {
    __shared__ int h[NBUCKET];
    int c = blockIdx.x, t = threadIdx.x;
    if (t < NBUCKET) h[t] = 0;
    __syncthreads();
    int beg = c * CE, end = min(beg + CE, NE);
    for (int e = beg + t; e < end; e += 256)
        atomicAdd(&h[ei[NE + e] / BSPAN], 1);
    __syncthreads();
    if (t < NBUCKET) cc[c * NBUCKET + t] = h[t];
}

// ---- A2: per-bucket exclusive scan over 2048 chunks (in-place on cc); tot[b] out ----
__global__ __launch_bounds__(256) void partA2_kernel(int* __restrict__ cc,
                                                     int* __restrict__ tot) {
    __shared__ int sh[256];
    int b = blockIdx.x, t = threadIdx.x;
    int v[8]; int s = 0;
#pragma unroll
    for (int i = 0; i < 8; ++i) { v[i] = cc[(t * 8 + i) * NBUCKET + b]; s += v[i]; }
    sh[t] = s; __syncthreads();
    for (int off = 1; off < 256; off <<= 1) {
        int x = (t >= off) ? sh[t - off] : 0; __syncthreads();
        sh[t] += x; __syncthreads();
    }
    int excl = sh[t] - s;
#pragma unroll
    for (int i = 0; i < 8; ++i) {
        cc[(t * 8 + i) * NBUCKET + b] = excl;
        excl += v[i];
    }
    if (t == 255) tot[b] = sh[255];
}

// ---- A3: scatter packed (local_dst<<17 | src) into COMPACT bucketed eb32 ----
__global__ __launch_bounds__(256) void partA3_kernel(const int* __restrict__ ei,
                                                     const int* __restrict__ cc,
                                                     const int* __restrict__ tot,
                                                     unsigned* __restrict__ eb32) {
    __shared__ int stot[NBUCKET];
    __shared__ int cur[NBUCKET];
    int c = blockIdx.x, t = threadIdx.x;
    if (t < NBUCKET) stot[t] = tot[t];
    __syncthreads();
    for (int off = 1; off < NBUCKET; off <<= 1) {
        int x = (t < NBUCKET && t >= off) ? stot[t - off] : 0;
        __syncthreads();
        if (t < NBUCKET) stot[t] += x;
        __syncthreads();
    }
    if (t < NBUCKET) cur[t] = (stot[t] - tot[t]) + cc[c * NBUCKET + t];
    __syncthreads();
    int beg = c * CE, end = min(beg + CE, NE);
    for (int e = beg + t; e < end; e += 256) {
        int d = ei[NE + e];
        int s = ei[e];
        int b = d / BSPAN;
        int ld = d - b * BSPAN;
        int p = atomicAdd(&cur[b], 1);
        eb32[p] = (unsigned)s | ((unsigned)ld << SRCBITS);
    }
}

// ---- B (fused): bucket hist -> offs + dinv -> CSR scatter (eb slice L2-hot) ----
__global__ __launch_bounds__(256) void partB_kernel(const unsigned* __restrict__ eb32,
                                                    const int* __restrict__ tot,
                                                    int* __restrict__ offs,
                                                    float* __restrict__ dinv,
                                                    int* __restrict__ csrc) {
    __shared__ int hcnt[BSPAN];
    __shared__ int lcur[BSPAN];
    __shared__ int sh[256];
    __shared__ int gbase_sh;
    int b = blockIdx.x, t = threadIdx.x;
    int lo = b * BSPAN;
    int span = min(BSPAN, NN - lo);
    if (span <= 0) return;
    for (int i = t; i < span; i += 256) hcnt[i] = 0;
    if (t == 0) {
        int g = 0;
        for (int i = 0; i < b; ++i) g += tot[i];
        gbase_sh = g;
    }
    __syncthreads();
    int gbase = gbase_sh;
    int len = tot[b];
    const unsigned* ebb = eb32 + (size_t)gbase;
    for (int e = t; e < len; e += 256)
        atomicAdd(&hcnt[ebb[e] >> SRCBITS], 1);
    __syncthreads();
    int base = t * 4;
    int v[4]; int s = 0;
#pragma unroll
    for (int j = 0; j < 4; ++j) { int i = base + j; v[j] = (i < span) ? hcnt[i] : 0; s += v[j]; }
    sh[t] = s; __syncthreads();
    for (int off = 1; off < 256; off <<= 1) {
        int x = (t >= off) ? sh[t - off] : 0; __syncthreads();
        sh[t] += x; __syncthreads();
    }
    int excl = sh[t] - s + gbase;
#pragma unroll
    for (int j = 0; j < 4; ++j) {
        int i = base + j;
        if (i < span) {
            offs[lo + i] = excl;
            lcur[i] = excl;
            dinv[lo + i] = rsqrtf((float)v[j] + 1.0f);
            excl += v[j];
        }
    }
    if (b == NBUCKET - 1 && t == 0) offs[NN] = NE;
    __syncthreads();
    for (int e = t; e < len; e += 256) {
        unsigned pr = ebb[e];
        int p = atomicAdd(&lcur[pr >> SRCBITS], 1);
        csrc[p] = (int)(pr & ((1u << SRCBITS) - 1));
    }
}

// ------- MFMA GEMM layer 0: reads f32 x directly (bf16 fragments in-register) -------
__global__ __launch_bounds__(256) void gemm_f32_kernel(const float* __restrict__ A,
                                                       const unsigned short* __restrict__ Wp,
                                                       const float* __restrict__ dinv,
                                                       unsigned char* __restrict__ out8,
                                                       int nrows) {
    __shared__ unsigned char f8s[64][128];
    int w = threadIdx.x >> 6;
    int l = threadIdx.x & 63;
    int m0 = blockIdx.x * 64 + w * 16;
    int kg = l >> 4;
    int cl = l & 15;
    int arow = m0 + cl;

    short8 a[4];
    if (arow < nrows) {
        const float4* Ar4 = (const float4*)(A + (size_t)arow * HH);
#pragma unroll
        for (int kb = 0; kb < 4; ++kb) {
            float4 u0 = Ar4[kb * 8 + kg * 2];
            float4 u1 = Ar4[kb * 8 + kg * 2 + 1];
            short8 tt;
            tt[0] = (short)f2bf(u0.x); tt[1] = (short)f2bf(u0.y);
            tt[2] = (short)f2bf(u0.z); tt[3] = (short)f2bf(u0.w);
            tt[4] = (short)f2bf(u1.x); tt[5] = (short)f2bf(u1.y);
            tt[6] = (short)f2bf(u1.z); tt[7] = (short)f2bf(u1.w);
            a[kb] = tt;
        }
    } else {
        short8 z = {};
#pragma unroll
        for (int kb = 0; kb < 4; ++kb) a[kb] = z;
    }

    float dv[4];
#pragma unroll
    for (int r = 0; r < 4; ++r) {
        int orow = m0 + kg * 4 + r;
        dv[r] = (orow < nrows) ? dinv[orow] : 0.f;
    }

#pragma unroll
    for (int cb = 0; cb < 8; ++cb) {
        f32x4 acc = {0.f, 0.f, 0.f, 0.f};
#pragma unroll
        for (int kb = 0; kb < 4; ++kb) {
            short8 b = *(const short8*)(Wp + (size_t)(cb * 4 + kb) * 512 + l * 8);
            acc = __builtin_amdgcn_mfma_f32_16x16x32_bf16(a[kb], b, acc, 0, 0, 0);
        }
#pragma unroll
        for (int r = 0; r < 4; ++r)
            f8s[w * 16 + kg * 4 + r][cb * 16 + cl] = f8enc1(acc[r] * dv[r]);
    }
    __syncthreads();
    int blk0 = blockIdx.x * 64;
    for (int u = threadIdx.x; u < 512; u += 256) {
        int row = u >> 3, c16 = u & 7;
        int grow = blk0 + row;
        if (grow < nrows)
            ((uint4*)out8)[(size_t)grow * 8 + c16] = ((const uint4*)&f8s[row][0])[c16];
    }
}

// ===== FUSED agg(layer l) + gemm(layer l+1): 32 nodes/block, no h8 round-trip =====
// NN == 3125*32 exactly, so no bounds checks (all threads reach barriers).
__global__ __launch_bounds__(256) void agg_gemm_kernel(const unsigned char* __restrict__ t8in,
                                                       const int* __restrict__ offs,
                                                       const int* __restrict__ csrc,
                                                       const float* __restrict__ dinv,
                                                       const float* __restrict__ bias,
                                                       const unsigned short* __restrict__ Wp,
                                                       unsigned char* __restrict__ t8out) {
    __shared__ unsigned char hbuf[32 * 256];   // 32 rows x 128 bf16, XOR-swizzled
    __shared__ unsigned char f8s[32][128];
    __shared__ float sdinv[32];
    int n0 = blockIdx.x * 32;
    int ln = threadIdx.x >> 3;                 // node slot 0..31
    int lane = threadIdx.x & 7;                // features lane*16..+15
    int n = n0 + ln;

    // ---- phase 1: aggregation (same as standalone agg) ----
    int beg = offs[n], end = offs[n + 1];
    const uint4* g16 = (const uint4*)t8in;
    f32x2 acc2[8] = {};
    f32x2 d2[4];
    int e = beg;
    for (; e + 7 < end; e += 8) {
        uint4 v[8];
#pragma unroll
        for (int q = 0; q < 8; ++q)
            v[q] = g16[(size_t)csrc[e + q] * 8 + lane];
#pragma unroll
        for (int q = 0; q < 8; ++q) {
            uint2 a, b;
            a.x = v[q].x; a.y = v[q].y; b.x = v[q].z; b.y = v[q].w;
            dec8p(a, d2);
#pragma unroll
            for (int k = 0; k < 4; ++k) acc2[k] += d2[k];
            dec8p(b, d2);
#pragma unroll
            for (int k = 0; k < 4; ++k) acc2[k + 4] += d2[k];
        }
    }
    for (; e <= end; ++e) {                    // includes self term at e==end
        int s = (e < end) ? csrc[e] : n;
        uint4 v = g16[(size_t)s * 8 + lane];
        uint2 a, b;
        a.x = v.x; a.y = v.y; b.x = v.z; b.y = v.w;
        dec8p(a, d2);
#pragma unroll
        for (int k = 0; k < 4; ++k) acc2[k] += d2[k];
        dec8p(b, d2);
#pragma unroll
        for (int k = 0; k < 4; ++k) acc2[k + 4] += d2[k];
    }
    float dn = dinv[n];
    if (lane == 0) sdinv[ln] = dn;
    const float4* bv = (const float4*)(bias + lane * 16);
    float bb[16];
    {
        float4 b0 = bv[0], b1 = bv[1], b2 = bv[2], b3 = bv[3];
        bb[0]=b0.x; bb[1]=b0.y; bb[2]=b0.z; bb[3]=b0.w;
        bb[4]=b1.x; bb[5]=b1.y; bb[6]=b1.z; bb[7]=b1.w;
        bb[8]=b2.x; bb[9]=b2.y; bb[10]=b2.z; bb[11]=b2.w;
        bb[12]=b3.x; bb[13]=b3.y; bb[14]=b3.z; bb[15]=b3.w;
    }
    float o[16];
#pragma unroll
    for (int j = 0; j < 16; ++j)
        o[j] = fmaxf(fmaf(acc2[j >> 1][j & 1], dn, bb[j]), 0.f);
    // store bf16 row to swizzled LDS (two 16B units)
    uint4 u0, u1;
    u0.x = pack2bf(o[0], o[1]);  u0.y = pack2bf(o[2], o[3]);
    u0.z = pack2bf(o[4], o[5]);  u0.w = pack2bf(o[6], o[7]);
    u1.x = pack2bf(o[8], o[9]);  u1.y = pack2bf(o[10], o[11]);
    u1.z = pack2bf(o[12], o[13]); u1.w = pack2bf(o[14], o[15]);
    unsigned swz = (unsigned)((ln & 7) << 4);
    unsigned base = (unsigned)ln * 256 + (unsigned)lane * 32;
    *(uint4*)(hbuf + ((base) ^ swz)) = u0;
    *(uint4*)(hbuf + ((base + 16) ^ swz)) = u1;
    __syncthreads();

    // ---- phase 2: next-layer GEMM on the 32 rows ----
    int wv = threadIdx.x >> 6;
    int l = threadIdx.x & 63;
    int rt = wv & 1;                           // row tile 0/1
    int ch = wv >> 1;                          // col half: cb = ch*4+q
    int kg = l >> 4;
    int cl = l & 15;
    int arow = rt * 16 + cl;
    unsigned rswz = (unsigned)((arow & 7) << 4);
    short8 a[4];
#pragma unroll
    for (int kb = 0; kb < 4; ++kb) {
        unsigned boff = (unsigned)arow * 256 + (unsigned)kb * 64 + (unsigned)kg * 16;
        a[kb] = *(const short8*)(hbuf + (boff ^ rswz));
    }
    float dv[4];
#pragma unroll
    for (int r = 0; r < 4; ++r) dv[r] = sdinv[rt * 16 + kg * 4 + r];
#pragma unroll
    for (int q = 0; q < 4; ++q) {
        int cb = ch * 4 + q;
        f32x4 acc = {0.f, 0.f, 0.f, 0.f};
#pragma unroll
        for (int kb = 0; kb < 4; ++kb) {
            short8 b = *(const short8*)(Wp + (size_t)(cb * 4 + kb) * 512 + l * 8);
            acc = __builtin_amdgcn_mfma_f32_16x16x32_bf16(a[kb], b, acc, 0, 0, 0);
        }
#pragma unroll
        for (int r = 0; r < 4; ++r)
            f8s[rt * 16 + kg * 4 + r][cb * 16 + cl] = f8enc1(acc[r] * dv[r]);
    }
    __syncthreads();
    int row2 = threadIdx.x >> 3, c16 = threadIdx.x & 7;   // 256 = 32 rows x 8
    ((uint4*)t8out)[(size_t)(n0 + row2) * 8 + c16] = ((const uint4*)&f8s[row2][0])[c16];
}

// ---- standalone aggregation (final layer -> h8 for pooling) ----
__global__ __launch_bounds__(256) void agg_relu_kernel(const unsigned char* __restrict__ t8,
                                                       const int* __restrict__ offs,
                                                       const int* __restrict__ csrc,
                                                       const float* __restrict__ dinv,
                                                       const float* __restrict__ bias,
                                                       unsigned char* __restrict__ hOut) {
    int n = blockIdx.x * 32 + (threadIdx.x >> 3);
    if (n >= NN) return;
    int lane = threadIdx.x & 7;
    int beg = offs[n], end = offs[n + 1];
    const uint4* g16 = (const uint4*)t8;
    f32x2 acc2[8] = {};
    f32x2 d2[4];
    int e = beg;
    for (; e + 7 < end; e += 8) {
        uint4 v[8];
#pragma unroll
        for (int q = 0; q < 8; ++q)
            v[q] = g16[(size_t)csrc[e + q] * 8 + lane];
#pragma unroll
        for (int q = 0; q < 8; ++q) {
            uint2 a, b;
            a.x = v[q].x; a.y = v[q].y; b.x = v[q].z; b.y = v[q].w;
            dec8p(a, d2);
#pragma unroll
            for (int k = 0; k < 4; ++k) acc2[k] += d2[k];
            dec8p(b, d2);
#pragma unroll
            for (int k = 0; k < 4; ++k) acc2[k + 4] += d2[k];
        }
    }
    for (; e <= end; ++e) {
        int s = (e < end) ? csrc[e] : n;
        uint4 v = g16[(size_t)s * 8 + lane];
        uint2 a, b;
        a.x = v.x; a.y = v.y; b.x = v.z; b.y = v.w;
        dec8p(a, d2);
#pragma unroll
        for (int k = 0; k < 4; ++k) acc2[k] += d2[k];
        dec8p(b, d2);
#pragma unroll
        for (int k = 0; k < 4; ++k) acc2[k + 4] += d2[k];
    }
    float dn = dinv[n];
    const float4* bv = (const float4*)(bias + lane * 16);
    float bb[16];
    float4 b0 = bv[0], b1 = bv[1], b2 = bv[2], b3 = bv[3];
    bb[0]=b0.x; bb[1]=b0.y; bb[2]=b0.z; bb[3]=b0.w;
    bb[4]=b1.x; bb[5]=b1.y; bb[6]=b1.z; bb[7]=b1.w;
    bb[8]=b2.x; bb[9]=b2.y; bb[10]=b2.z; bb[11]=b2.w;
    bb[12]=b3.x; bb[13]=b3.y; bb[14]=b3.z; bb[15]=b3.w;
    float o[16];
#pragma unroll
    for (int j = 0; j < 16; ++j)
        o[j] = fmaxf(fmaf(acc2[j >> 1][j & 1], dn, bb[j]), 0.f);
    uint4 w;
    w.x = enc_pk4(o[0], o[1], o[2], o[3]);
    w.y = enc_pk4(o[4], o[5], o[6], o[7]);
    w.z = enc_pk4(o[8], o[9], o[10], o[11]);
    w.w = enc_pk4(o[12], o[13], o[14], o[15]);
    ((uint4*)hOut)[(size_t)n * 8 + lane] = w;
}

// -------- pooling stage 1: 16 segments/graph, partials to psum_seg (no atomics) --------
__global__ __launch_bounds__(256) void poolseg_kernel(const unsigned char* __restrict__ h8,
                                                      const int* __restrict__ batch,
                                                      float* __restrict__ psum_seg) {
    int g = blockIdx.x >> 4;
    int seg = blockIdx.x & (PSEG - 1);
    int t = threadIdx.x;
    int lo = 0, hi = NN;
    while (lo < hi) { int m = (lo + hi) >> 1; if (batch[m] < g) lo = m + 1; else hi = m; }
    int lb = lo;
    lo = 0; hi = NN;
    while (lo < hi) { int m = (lo + hi) >> 1; if (batch[m] <= g) lo = m + 1; else hi = m; }
    int ub = lo;
    int len = ub - lb;
    int b0 = lb + (int)(((long long)len * seg) / PSEG);
    int b1 = lb + (int)(((long long)len * (seg + 1)) / PSEG);

    int fg = t & 15;
    int rg = t >> 4;
    const uint2* gp = (const uint2*)h8;
    f32x2 acc2[4] = {};
    f32x2 d2[4];
    for (int n = b0 + rg; n < b1; n += 16) {
        uint2 v = gp[(size_t)n * 16 + fg];
        dec8p(v, d2);
#pragma unroll
        for (int k = 0; k < 4; ++k) acc2[k] += d2[k];
    }
    __shared__ float red[256][8];
#pragma unroll
    for (int j = 0; j < 8; ++j) red[t][j] = acc2[j >> 1][j & 1];
    __syncthreads();
    for (int off = 8; off >= 1; off >>= 1) {
        if (rg < off) {
#pragma unroll
            for (int j = 0; j < 8; ++j) red[t][j] += red[t + off * 16][j];
        }
        __syncthreads();
    }
    if (t < 16) {
#pragma unroll
        for (int j = 0; j < 8; ++j)
            psum_seg[((size_t)g * PSEG + seg) * HH + t * 8 + j] = red[t][j];
    }
}

// -------- pooling stage 2 + MLP + log_softmax: one block per graph --------
__global__ __launch_bounds__(128) void mlp2_kernel(const float* __restrict__ psum_seg,
                                                   const int* __restrict__ batch,
                                                   const float* __restrict__ Wl1,
                                                   const float* __restrict__ bl1,
                                                   const float* __restrict__ Wl2,
                                                   const float* __restrict__ bl2,
                                                   float* __restrict__ out) {
    __shared__ float p[128], o1[128], lg[CC];
    int g = blockIdx.x, t = threadIdx.x;
    int lo = 0, hi = NN;
    while (lo < hi) { int m = (lo + hi) >> 1; if (batch[m] < g) lo = m + 1; else hi = m; }
    int lb = lo;
    lo = 0; hi = NN;
    while (lo < hi) { int m = (lo + hi) >> 1; if (batch[m] <= g) lo = m + 1; else hi = m; }
    int len = lo - lb;
    float a = 0.f;
#pragma unroll
    for (int s = 0; s < PSEG; ++s)
        a += psum_seg[((size_t)g * PSEG + s) * HH + t];
    p[t] = a / fmaxf((float)len, 1.f);
    __syncthreads();
    float acc = bl1[t];
    for (int k = 0; k < HH; ++k) acc = fmaf(p[k], Wl1[k * HH + t], acc);
    o1[t] = fmaxf(acc, 0.f);
    __syncthreads();
    if (t < CC) {
        float a2 = bl2[t];
        for (int j = 0; j < HH; ++j) a2 = fmaf(o1[j], Wl2[j * CC + t], a2);
        lg[t] = a2;
    }
    __syncthreads();
    if (t == 0) {
        float m = lg[0];
        for (int c = 1; c < CC; ++c) m = fmaxf(m, lg[c]);
        float s = 0.f;
        for (int c = 0; c < CC; ++c) s += expf(lg[c] - m);
        float ls = logf(s);
        for (int c = 0; c < CC; ++c) out[g * CC + c] = lg[c] - m - ls;
    }
}

extern "C" void kernel_launch(void* const* d_in, const int* in_sizes, int n_in,
                              void* d_out, int out_size, void* d_ws, size_t ws_size,
                              hipStream_t stream) {
    const float* x   = (const float*)d_in[0];
    const int*   ei  = (const int*)d_in[1];
    const int*   bat = (const int*)d_in[2];
    const float* W1  = (const float*)d_in[3];
    const float* b1  = (const float*)d_in[4];
    const float* Wr1 = (const float*)d_in[5];
    const float* br1 = (const float*)d_in[6];
    const float* W2  = (const float*)d_in[7];
    const float* b2  = (const float*)d_in[8];
    const float* Wr  = (const float*)d_in[9];
    const float* br  = (const float*)d_in[10];
    const float* Wl1 = (const float*)d_in[11];
    const float* bl1 = (const float*)d_in[12];
    const float* Wl2 = (const float*)d_in[13];
    const float* bl2 = (const float*)d_in[14];
    float* out = (float*)d_out;

    // workspace carve-up (256B aligned)
    char* base = (char*)d_ws;
    size_t off = 0;
    auto alloc = [&](size_t bytes) {
        void* p = base + off;
        off += (bytes + 255) & ~(size_t)255;
        return p;
    };
    unsigned char* t8a  = (unsigned char*)alloc((size_t)NN * HH);
    unsigned char* t8b  = (unsigned char*)alloc((size_t)NN * HH);
    unsigned char* h8   = (unsigned char*)alloc((size_t)NN * HH);
    unsigned* eb32 = (unsigned*)alloc((size_t)NE * 4);
    int*   cc     = (int*)alloc((size_t)NCHUNK * NBUCKET * 4);
    int*   csrc   = (int*)alloc((size_t)NE * 4);
    int*   offs   = (int*)alloc((size_t)(NN + 1) * 4);
    float* dinv   = (float*)alloc((size_t)NN * 4);
    int*   tot    = (int*)alloc(NBUCKET * 4);
    unsigned short* Wpack = (unsigned short*)alloc(3 * 16384 * 2);
    float* bc     = (float*)alloc(3 * HH * 4);
    float* psum_seg = (float*)alloc((size_t)GG * PSEG * HH * 4);
    (void)ws_size; (void)in_sizes; (void)n_in; (void)out_size;

    // weight combine
    combw_kernel<<<192, 256, 0, stream>>>(W1, b1, Wr1, br1, W2, b2, Wr, br, Wpack, bc);

    // deterministic partition: 4 kernels, no global atomics
    partA1_kernel<<<NCHUNK, 256, 0, stream>>>(ei, cc);
    partA2_kernel<<<NBUCKET, 256, 0, stream>>>(cc, tot);
    partA3_kernel<<<NCHUNK, 256, 0, stream>>>(ei, cc, tot, eb32);
    partB_kernel<<<NBUCKET, 256, 0, stream>>>(eb32, tot, offs, dinv, csrc);

    const int GEMM_BLOCKS = (NN + 63) / 64;
    const int FUSE_BLOCKS = NN / 32;   // 3125, exact
    // layer 0 GEMM (f32 x direct)
    gemm_f32_kernel<<<GEMM_BLOCKS, 256, 0, stream>>>(x, Wpack, dinv, t8a, NN);
    // fused agg(L0)+gemm(L1): t8a -> t8b   (h kept as bf16 in LDS, no h8 round-trip)
    agg_gemm_kernel<<<FUSE_BLOCKS, 256, 0, stream>>>(t8a, offs, csrc, dinv, bc,
                                                     Wpack + 16384, t8b);
    // fused agg(L1)+gemm(L2): t8b -> t8a
    agg_gemm_kernel<<<FUSE_BLOCKS, 256, 0, stream>>>(t8b, offs, csrc, dinv, bc + HH,
                                                     Wpack + 2 * 16384, t8a);
    // final aggregation -> h8 (fp8) for pooling
    agg_relu_kernel<<<FUSE_BLOCKS, 256, 0, stream>>>(t8a, offs, csrc, dinv, bc + 2 * HH, h8);

    // pooling (parallel segments, no atomics) + readout
    poolseg_kernel<<<GG * PSEG, 256, 0, stream>>>(h8, bat, psum_seg);
    mlp2_kernel<<<GG, 128, 0, stream>>>(psum_seg, bat, Wl1, bl1, Wl2, bl2, out);
}